// Round 12
// baseline (1091.022 us; speedup 1.0000x reference)
//
#include <hip/hip_runtime.h>
#include <hip/hip_bf16.h>

typedef short v8s __attribute__((ext_vector_type(8)));
typedef unsigned short v8u __attribute__((ext_vector_type(8)));
typedef float v4f __attribute__((ext_vector_type(4)));
typedef unsigned short u16;

#define LL 1024
#define DD 1024

static __device__ __forceinline__ u16 f2b(float x) {
  __hip_bfloat16 h = __float2bfloat16(x);
  return __builtin_bit_cast(u16, h);
}
static __device__ __forceinline__ float b2f(u16 u) {
  unsigned int x = ((unsigned int)u) << 16;
  return __builtin_bit_cast(float, x);
}

static __device__ __forceinline__ void gload_lds16(const u16* g, u16* l) {
  __builtin_amdgcn_global_load_lds((const __attribute__((address_space(1))) void*)g,
                                   (__attribute__((address_space(3))) void*)l, 16, 0, 0);
}

// ---------------- f32 -> bf16 conversion (3 tensors per launch via grid.y) ----
__global__ __launch_bounds__(256) void cvt3(const float* __restrict__ p0,
                                            const float* __restrict__ p1,
                                            const float* __restrict__ p2,
                                            u16* __restrict__ out, int n8, long ostride) {
  const float* src = blockIdx.y == 0 ? p0 : (blockIdx.y == 1 ? p1 : p2);
  u16* dst = out + (long)blockIdx.y * ostride;
  int i = blockIdx.x * 256 + threadIdx.x;
  if (i >= n8) return;
  const float4* p = (const float4*)src + (long)i * 2;
  float4 a = p[0], b = p[1];
  v8u r;
  r[0] = f2b(a.x); r[1] = f2b(a.y); r[2] = f2b(a.z); r[3] = f2b(a.w);
  r[4] = f2b(b.x); r[5] = f2b(b.y); r[6] = f2b(b.z); r[7] = f2b(b.w);
  *((v8u*)dst + i) = r;
}

// ---------------- per-head counting sort of q-rows by effective valid len ----
__global__ __launch_bounds__(256) void sortperm(const int* __restrict__ valid,
                                                u16* __restrict__ perm) {
  __shared__ int hist[1024];
  __shared__ int wsum[4];
  const int bh = blockIdx.x;
  const int tid = threadIdx.x;
  const int* v = valid + bh * 1024;
  for (int i = tid; i < 1024; i += 256) hist[i] = 0;
  __syncthreads();
  for (int i = tid; i < 1024; i += 256) {
    int k = v[i];
    k = (k == 0) ? 1023 : (k - 1);  // bin = eff-1
    atomicAdd(&hist[k], 1);
  }
  __syncthreads();
  const int base = tid * 4;
  int h0 = hist[base], h1 = hist[base + 1], h2 = hist[base + 2], h3 = hist[base + 3];
  int local = h0 + h1 + h2 + h3;
  const int lane = tid & 63, w = tid >> 6;
  int scan = local;
#pragma unroll
  for (int d = 1; d < 64; d <<= 1) {
    int t = __shfl_up(scan, d);
    if (lane >= d) scan += t;
  }
  if (lane == 63) wsum[w] = scan;
  __syncthreads();
  int woff = 0;
  for (int i = 0; i < w; ++i) woff += wsum[i];
  int excl = woff + scan - local;
  hist[base] = excl;
  hist[base + 1] = excl + h0;
  hist[base + 2] = excl + h0 + h1;
  hist[base + 3] = excl + h0 + h1 + h2;
  __syncthreads();
  for (int i = tid; i < 1024; i += 256) {
    int k = v[i];
    k = (k == 0) ? 1023 : (k - 1);
    int pos = atomicAdd(&hist[k], 1);
    perm[bh * 1024 + pos] = (u16)i;
  }
}

// ---------------- C[M,N] = A[M,K] * B[N,K]^T  (bf16 in, OUTT out) -------------
template <typename OUTT>
__global__ __launch_bounds__(256) void gemm_bt(const u16* __restrict__ A,
                                               const u16* __restrict__ Bw,
                                               OUTT* __restrict__ C,
                                               long za, long zb, long zc) {
  __shared__ u16 As[128 * 64];
  __shared__ u16 Bs[128 * 64];
  A += (long)blockIdx.z * za;
  Bw += (long)blockIdx.z * zb;
  C += (long)blockIdx.z * zc;
  const int tid = threadIdx.x;
  const int lane = tid & 63;
  const int l15 = lane & 15, lg = lane >> 4;
  const int wid = tid >> 6;
  const int wm = wid >> 1, wn = wid & 1;
  const long mbase = (long)blockIdx.y * 128;
  const long nbase = (long)blockIdx.x * 128;

  const u16* ap = A + (mbase + (tid >> 3)) * 1024 + (tid & 7) * 8;
  const u16* bp = Bw + (nbase + (tid >> 3)) * 1024 + (tid & 7) * 8;

  v4f acc[4][4] = {};

  for (int kt = 0; kt < 16; ++kt) {
    __syncthreads();
#pragma unroll
    for (int j = 0; j < 4; ++j) {
      gload_lds16(ap + kt * 64 + j * 32 * 1024, &As[(tid + 256 * j) * 8]);
      gload_lds16(bp + kt * 64 + j * 32 * 1024, &Bs[(tid + 256 * j) * 8]);
    }
    __syncthreads();
#pragma unroll
    for (int kk = 0; kk < 2; ++kk) {
      v8s a[4], b[4];
#pragma unroll
      for (int i = 0; i < 4; ++i)
        a[i] = *(const v8s*)&As[(wm * 64 + i * 16 + l15) * 64 + kk * 32 + lg * 8];
#pragma unroll
      for (int i = 0; i < 4; ++i)
        b[i] = *(const v8s*)&Bs[(wn * 64 + i * 16 + l15) * 64 + kk * 32 + lg * 8];
#pragma unroll
      for (int mi = 0; mi < 4; ++mi)
#pragma unroll
        for (int nj = 0; nj < 4; ++nj)
          acc[mi][nj] = __builtin_amdgcn_mfma_f32_16x16x32_bf16(a[mi], b[nj], acc[mi][nj], 0, 0, 0);
    }
  }
#pragma unroll
  for (int mi = 0; mi < 4; ++mi) {
#pragma unroll
    for (int r = 0; r < 4; ++r) {
      long row = mbase + wm * 64 + mi * 16 + lg * 4 + r;
#pragma unroll
      for (int nj = 0; nj < 4; ++nj) {
        long col = nbase + wn * 64 + nj * 16 + l15;
        if constexpr (__is_same(OUTT, float))
          C[row * 1024 + col] = acc[mi][nj][r];
        else
          C[row * 1024 + col] = f2b(acc[mi][nj][r]);
      }
    }
  }
}

// ---------------- fused masked attention, split-K, ABLATION TEMPLATE ----------
// V=0 full (real output, REP=1). Diagnostics (REP=4 so they dominate top-5):
// V=1 no-SOFTMAX, V=2 no-PV(+Ps), V=3 no-STAGE(no loads,no commit,zeroed LDS),
// V=4 no-QKT(synth s), V=5 loads-kept/NO-COMMIT (splits staging: loads vs LDS).
template <int V, int REP>
__global__ __launch_bounds__(256) void attn_kern(const u16* __restrict__ qb,
                                                 const u16* __restrict__ kb,
                                                 const u16* __restrict__ vb,
                                                 const int* __restrict__ valid,
                                                 const u16* __restrict__ perm,
                                                 u16* __restrict__ partO,
                                                 float* __restrict__ partM,
                                                 float* __restrict__ partL) {
  constexpr bool DO_LOADS = (V != 3);
  constexpr bool DO_COMMIT = (V != 3) && (V != 5);
  constexpr bool DO_QKT = (V != 4);
  constexpr bool DO_SM = (V != 1);
  constexpr bool DO_PV = (V != 2);

  __shared__ u16 Ks[64 * 72];
  __shared__ u16 Vt[64 * 72];
  __shared__ u16 Ps[4][16 * 72];

  const int tid = threadIdx.x;
  const int lane = tid & 63;
  const int wid = tid >> 6;
  const int l15 = lane & 15, lg = lane >> 4;
  const int bh = blockIdx.y;
  const int b = bh >> 4, h = bh & 15;
  const long headoff = ((long)b * LL) * DD + h * 64;
  const int xx = blockIdx.x;
  const int gq = 15 - (xx >> 1);
  const int ch = xx & 1;
  const u16* pblk = perm + bh * 1024 + gq * 64;

  const int lastv = valid[bh * LL + pblk[63]];
  const int ntiles = ((lastv == 0 ? LL : lastv) + 63) >> 6;
  const int kt0 = ch * 8;
  const int kt1 = min(ntiles, kt0 + 8);
  if (kt0 >= kt1) return;
  const int slot = (bh * 16 + gq) * 2 + ch;

  const u16* pp = pblk + wid * 16;

  const int qrowA = pp[l15];
  v8s qf[2];
#pragma unroll
  for (int ks = 0; ks < 2; ++ks)
    qf[ks] = *(const v8s*)(qb + headoff + (long)qrowA * DD + ks * 32 + lg * 8);

  int vraw[4];
#pragma unroll
  for (int r = 0; r < 4; ++r) vraw[r] = valid[bh * LL + pp[lg * 4 + r]];

  float mrow[4], lrow[4];
  v4f oacc[4] = {};
#pragma unroll
  for (int r = 0; r < 4; ++r) { mrow[r] = -1e30f; lrow[r] = 0.0f; }

  const int kk = tid & 63;
  const int qtr = tid >> 6;
  const long stagebase = headoff + (long)kk * DD + qtr * 16;

  if constexpr (!DO_COMMIT) {
    // zero LDS once so QKT/PV behave like steady-state
    for (int i = tid; i < 64 * 72; i += 256) { Ks[i] = 0; Vt[i] = 0; }
    __syncthreads();
  }

  v8s rk0{}, rk1{}, rv0{}, rv1{};
  if constexpr (DO_LOADS) {
    rk0 = *(const v8s*)(kb + stagebase + (long)kt0 * 64 * DD);
    rk1 = *(const v8s*)(kb + stagebase + (long)kt0 * 64 * DD + 8);
    rv0 = *(const v8s*)(vb + stagebase + (long)kt0 * 64 * DD);
    rv1 = *(const v8s*)(vb + stagebase + (long)kt0 * 64 * DD + 8);
  }

  for (int rep = 0; rep < REP; ++rep) {
    for (int kt = kt0; kt < kt1; ++kt) {
      // ---- barrier A (WAR guard)
      __builtin_amdgcn_sched_barrier(0);
      __builtin_amdgcn_s_barrier();
      __builtin_amdgcn_sched_barrier(0);

      if constexpr (DO_COMMIT) {
        *(v8s*)&Ks[kk * 72 + qtr * 16] = rk0;
        *(v8s*)&Ks[kk * 72 + qtr * 16 + 8] = rk1;
        {
          v8u u0 = __builtin_bit_cast(v8u, rv0);
          v8u u1 = __builtin_bit_cast(v8u, rv1);
#pragma unroll
          for (int j = 0; j < 8; ++j) Vt[(qtr * 16 + j) * 72 + kk] = u0[j];
#pragma unroll
          for (int j = 0; j < 8; ++j) Vt[(qtr * 16 + 8 + j) * 72 + kk] = u1[j];
        }
      }
      if constexpr (DO_LOADS) {
        if (kt + 1 < kt1) {
          const long noff = stagebase + (long)(kt + 1) * 64 * DD;
          rk0 = *(const v8s*)(kb + noff);
          rk1 = *(const v8s*)(kb + noff + 8);
          rv0 = *(const v8s*)(vb + noff);
          rv1 = *(const v8s*)(vb + noff + 8);
        }
      }
      if constexpr (DO_LOADS && !DO_COMMIT) {
        // keep loads alive without consuming them (rule #17)
        asm volatile("" ::"v"((short)rk0[0]), "v"((short)rk1[0]),
                         "v"((short)rv0[0]), "v"((short)rv1[0]));
      }
      // ---- barrier B
      asm volatile("s_waitcnt lgkmcnt(0)" ::: "memory");
      __builtin_amdgcn_sched_barrier(0);
      __builtin_amdgcn_s_barrier();
      __builtin_amdgcn_sched_barrier(0);

      // S = Q K^T (or synthetic when no-QKT)
      v4f s[4];
      if constexpr (DO_QKT) {
        __builtin_amdgcn_s_setprio(1);
#pragma unroll
        for (int t = 0; t < 4; ++t) {
          v4f z = {};
#pragma unroll
          for (int ks = 0; ks < 2; ++ks) {
            v8s kf = *(const v8s*)&Ks[(t * 16 + l15) * 72 + ks * 32 + lg * 8];
            z = __builtin_amdgcn_mfma_f32_16x16x32_bf16(qf[ks], kf, z, 0, 0, 0);
          }
          s[t] = z;
        }
        __builtin_amdgcn_s_setprio(0);
      } else {
#pragma unroll
        for (int t = 0; t < 4; ++t)
#pragma unroll
          for (int r = 0; r < 4; ++r)
            s[t][r] = (float)(lane + t * 4 + r + (kt & 3)) * 0.03125f;
      }

      // scale into log2 domain + mask
      const float SC = 0.18033688f;  // (1/8) * log2(e)
      const int colbase = kt * 64 + l15;
#pragma unroll
      for (int t = 0; t < 4; ++t)
#pragma unroll
        for (int r = 0; r < 4; ++r) {
          float val = s[t][r] * SC;
          s[t][r] = (colbase + t * 16 < vraw[r]) ? val : -1e6f;
        }

      if constexpr (DO_SM) {
        float pm[4];
#pragma unroll
        for (int r = 0; r < 4; ++r)
          pm[r] = fmaxf(fmaxf(s[0][r], s[1][r]), fmaxf(s[2][r], s[3][r]));
#pragma unroll
        for (int d = 1; d < 16; d <<= 1)
#pragma unroll
          for (int r = 0; r < 4; ++r) pm[r] = fmaxf(pm[r], __shfl_xor(pm[r], d));

        bool sk = true;
#pragma unroll
        for (int r = 0; r < 4; ++r) sk = sk && (pm[r] <= mrow[r] + 11.0f);
        if (!__all(sk)) {
#pragma unroll
          for (int r = 0; r < 4; ++r) {
            float mn = fmaxf(mrow[r], pm[r]);
            float sc = __builtin_amdgcn_exp2f(mrow[r] - mn);
            mrow[r] = mn;
            lrow[r] *= sc;
#pragma unroll
            for (int t = 0; t < 4; ++t) oacc[t][r] *= sc;
          }
        }
        float rs[4] = {0.f, 0.f, 0.f, 0.f};
#pragma unroll
        for (int t = 0; t < 4; ++t)
#pragma unroll
          for (int r = 0; r < 4; ++r) {
            float p = __builtin_amdgcn_exp2f(s[t][r] - mrow[r]);
            s[t][r] = p;
            rs[r] += p;
          }
#pragma unroll
        for (int d = 1; d < 16; d <<= 1)
#pragma unroll
          for (int r = 0; r < 4; ++r) rs[r] += __shfl_xor(rs[r], d);
#pragma unroll
        for (int r = 0; r < 4; ++r) lrow[r] += rs[r];
      }

      if constexpr (DO_PV) {
        // P -> bf16 -> per-wave LDS, then consume as MFMA A-operand
#pragma unroll
        for (int t = 0; t < 4; ++t)
#pragma unroll
          for (int r = 0; r < 4; ++r)
            Ps[wid][(lg * 4 + r) * 72 + t * 16 + l15] = f2b(s[t][r]);

        asm volatile("s_waitcnt lgkmcnt(0)" ::: "memory");
        __builtin_amdgcn_sched_barrier(0);

        __builtin_amdgcn_s_setprio(1);
#pragma unroll
        for (int ks = 0; ks < 2; ++ks) {
          v8s pa = *(const v8s*)&Ps[wid][l15 * 72 + ks * 32 + lg * 8];
#pragma unroll
          for (int t = 0; t < 4; ++t) {
            v8s vf = *(const v8s*)&Vt[(t * 16 + l15) * 72 + ks * 32 + lg * 8];
            oacc[t] = __builtin_amdgcn_mfma_f32_16x16x32_bf16(pa, vf, oacc[t], 0, 0, 0);
          }
        }
        __builtin_amdgcn_s_setprio(0);
      } else {
        // keep s (and thus QKT+SM) live without consuming it (rule #17)
#pragma unroll
        for (int t = 0; t < 4; ++t)
#pragma unroll
          for (int r = 0; r < 4; ++r)
            asm volatile("" ::"v"(s[t][r]));
      }
    }
  }

  if constexpr (!DO_SM) {
#pragma unroll
    for (int r = 0; r < 4; ++r) lrow[r] = 1.0f;
  }

  // epilogue: write UNNORMALIZED partials (sorted-row order); merge normalizes
  u16* po = partO + (long)slot * 4096;
  float* pmv = partM + slot * 64;
  float* plv = partL + slot * 64;
#pragma unroll
  for (int r = 0; r < 4; ++r) {
    int p = wid * 16 + lg * 4 + r;
    pmv[p] = mrow[r];
    plv[p] = lrow[r];
#pragma unroll
    for (int t = 0; t < 4; ++t)
      po[p * 64 + t * 16 + l15] = f2b(oacc[t][r]);
  }
}

// ---------------- merge the (up to 2) chunk partials per (bh, group) ----------
__global__ __launch_bounds__(256) void merge_kern(const int* __restrict__ valid,
                                                  const u16* __restrict__ perm,
                                                  const u16* __restrict__ partO,
                                                  const float* __restrict__ partM,
                                                  const float* __restrict__ partL,
                                                  u16* __restrict__ ob) {
  const int g = blockIdx.x, bh = blockIdx.y;
  const int b = bh >> 4, h = bh & 15;
  const u16* pblk = perm + bh * 1024 + g * 64;
  const int lastv = valid[bh * LL + pblk[63]];
  const int ntiles = ((lastv == 0 ? LL : lastv) + 63) >> 6;
  const bool has1 = ntiles > 8;
  const int p = threadIdx.x >> 2;
  const int q4 = (threadIdx.x & 3) * 16;
  const int s0 = (bh * 16 + g) * 2;

  float m0 = partM[s0 * 64 + p], l0 = partL[s0 * 64 + p];
  float w0 = 1.0f, w1 = 0.0f, L = l0;
  if (has1) {
    float m1 = partM[(s0 + 1) * 64 + p], l1 = partL[(s0 + 1) * 64 + p];
    float M = fmaxf(m0, m1);
    w0 = __builtin_amdgcn_exp2f(m0 - M);
    w1 = __builtin_amdgcn_exp2f(m1 - M);
    L = l0 * w0 + l1 * w1;
  }
  const float inv = 1.0f / L;

  const u16* po0 = partO + (long)s0 * 4096 + p * 64 + q4;
  float acc[16];
  {
    v8u x0 = *(const v8u*)po0;
    v8u x1 = *(const v8u*)(po0 + 8);
#pragma unroll
    for (int j = 0; j < 8; ++j) acc[j] = b2f(x0[j]) * w0;
#pragma unroll
    for (int j = 0; j < 8; ++j) acc[8 + j] = b2f(x1[j]) * w0;
  }
  if (has1) {
    const u16* po1 = po0 + 4096;
    v8u y0 = *(const v8u*)po1;
    v8u y1 = *(const v8u*)(po1 + 8);
#pragma unroll
    for (int j = 0; j < 8; ++j) acc[j] += b2f(y0[j]) * w1;
#pragma unroll
    for (int j = 0; j < 8; ++j) acc[8 + j] += b2f(y1[j]) * w1;
  }
  const int orow = pblk[p];
  u16* dst = ob + ((long)b * LL + orow) * DD + h * 64 + q4;
#pragma unroll
  for (int j = 0; j < 16; ++j) dst[j] = f2b(acc[j] * inv);
}

// ---------------- launch ------------------------------------------------------
extern "C" void kernel_launch(void* const* d_in, const int* in_sizes, int n_in,
                              void* d_out, int out_size, void* d_ws, size_t ws_size,
                              hipStream_t stream) {
  const float* Q = (const float*)d_in[0];
  const float* K = (const float*)d_in[1];
  const float* V = (const float*)d_in[2];
  const int* valid = (const int*)d_in[3];
  const float* Wq = (const float*)d_in[4];
  const float* Wk = (const float*)d_in[5];
  const float* Wv = (const float*)d_in[6];
  const float* Wo = (const float*)d_in[7];
  float* out = (float*)d_out;

  u16* ws = (u16*)d_ws;
  const long MK = 4096L * 1024;
  const long NK = 1024L * 1024;
  u16* qkvb = ws;
  u16* wqkv = qkvb + 3 * MK;
  u16* wo = wqkv + 3 * NK;
  u16* proj = wo + NK;
  u16* ob = proj + 3 * MK;
  u16* perm = wqkv;                              // dead after proj GEMM
  u16* partO = qkvb;                             // dead after proj GEMM
  float* partM = (float*)(qkvb + 2048L * 4096);
  float* partL = partM + 2048L * 64;

  cvt3<<<dim3(2048, 3), 256, 0, stream>>>(Q, K, V, qkvb, (int)(MK / 8), MK);
  cvt3<<<dim3(512, 3), 256, 0, stream>>>(Wq, Wk, Wv, wqkv, (int)(NK / 8), NK);
  cvt3<<<dim3(512, 1), 256, 0, stream>>>(Wo, Wo, Wo, wo, (int)(NK / 8), 0);

  gemm_bt<u16><<<dim3(8, 32, 3), 256, 0, stream>>>(qkvb, wqkv, proj, MK, NK, MK);
  sortperm<<<64, 256, 0, stream>>>(valid, perm);
  attn_kern<0, 1><<<dim3(32, 64), 256, 0, stream>>>(proj, proj + MK, proj + 2 * MK, valid,
                                                    perm, partO, partM, partL);
  merge_kern<<<dim3(16, 64), 256, 0, stream>>>(valid, perm, partO, partM, partL, ob);
  gemm_bt<float><<<dim3(8, 32, 1), 256, 0, stream>>>(ob, wo, out, 0, 0, 0);

  // ---- diagnostic ablations, REP=4 so each dispatch exceeds the replayed V0
  // crowd and surfaces in top-5 with its counter signature. partO/partM/partL
  // are dead here (rewritten by attn_kern<0> before merge each call).
  attn_kern<1, 4><<<dim3(32, 64), 256, 0, stream>>>(proj, proj + MK, proj + 2 * MK, valid,
                                                    perm, partO, partM, partL);
  attn_kern<2, 4><<<dim3(32, 64), 256, 0, stream>>>(proj, proj + MK, proj + 2 * MK, valid,
                                                    perm, partO, partM, partL);
  attn_kern<3, 4><<<dim3(32, 64), 256, 0, stream>>>(proj, proj + MK, proj + 2 * MK, valid,
                                                    perm, partO, partM, partL);
  attn_kern<4, 4><<<dim3(32, 64), 256, 0, stream>>>(proj, proj + MK, proj + 2 * MK, valid,
                                                    perm, partO, partM, partL);
  attn_kern<5, 4><<<dim3(32, 64), 256, 0, stream>>>(proj, proj + MK, proj + 2 * MK, valid,
                                                    perm, partO, partM, partL);
}

// Round 14
// 179.046 us; speedup vs baseline: 6.0935x; 6.0935x over previous
//
#include <hip/hip_runtime.h>
#include <hip/hip_bf16.h>

typedef short v8s __attribute__((ext_vector_type(8)));
typedef unsigned short v8u __attribute__((ext_vector_type(8)));
typedef float v4f __attribute__((ext_vector_type(4)));
typedef unsigned short u16;

#define LL 1024
#define DD 1024

static __device__ __forceinline__ u16 f2b(float x) {
  __hip_bfloat16 h = __float2bfloat16(x);
  return __builtin_bit_cast(u16, h);
}
static __device__ __forceinline__ float b2f(u16 u) {
  unsigned int x = ((unsigned int)u) << 16;
  return __builtin_bit_cast(float, x);
}

static __device__ __forceinline__ void gload_lds16(const u16* g, u16* l) {
  __builtin_amdgcn_global_load_lds((const __attribute__((address_space(1))) void*)g,
                                   (__attribute__((address_space(3))) void*)l, 16, 0, 0);
}

// ---------------- f32 -> bf16 conversion (3 tensors per launch via grid.y) ----
__global__ __launch_bounds__(256) void cvt3(const float* __restrict__ p0,
                                            const float* __restrict__ p1,
                                            const float* __restrict__ p2,
                                            u16* __restrict__ out, int n8, long ostride) {
  const float* src = blockIdx.y == 0 ? p0 : (blockIdx.y == 1 ? p1 : p2);
  u16* dst = out + (long)blockIdx.y * ostride;
  int i = blockIdx.x * 256 + threadIdx.x;
  if (i >= n8) return;
  const float4* p = (const float4*)src + (long)i * 2;
  float4 a = p[0], b = p[1];
  v8u r;
  r[0] = f2b(a.x); r[1] = f2b(a.y); r[2] = f2b(a.z); r[3] = f2b(a.w);
  r[4] = f2b(b.x); r[5] = f2b(b.y); r[6] = f2b(b.z); r[7] = f2b(b.w);
  *((v8u*)dst + i) = r;
}

// ---------------- per-head counting sort of q-rows by effective valid len ----
__global__ __launch_bounds__(256) void sortperm(const int* __restrict__ valid,
                                                u16* __restrict__ perm) {
  __shared__ int hist[1024];
  __shared__ int wsum[4];
  const int bh = blockIdx.x;
  const int tid = threadIdx.x;
  const int* v = valid + bh * 1024;
  for (int i = tid; i < 1024; i += 256) hist[i] = 0;
  __syncthreads();
  for (int i = tid; i < 1024; i += 256) {
    int k = v[i];
    k = (k == 0) ? 1023 : (k - 1);  // bin = eff-1
    atomicAdd(&hist[k], 1);
  }
  __syncthreads();
  const int base = tid * 4;
  int h0 = hist[base], h1 = hist[base + 1], h2 = hist[base + 2], h3 = hist[base + 3];
  int local = h0 + h1 + h2 + h3;
  const int lane = tid & 63, w = tid >> 6;
  int scan = local;
#pragma unroll
  for (int d = 1; d < 64; d <<= 1) {
    int t = __shfl_up(scan, d);
    if (lane >= d) scan += t;
  }
  if (lane == 63) wsum[w] = scan;
  __syncthreads();
  int woff = 0;
  for (int i = 0; i < w; ++i) woff += wsum[i];
  int excl = woff + scan - local;
  hist[base] = excl;
  hist[base + 1] = excl + h0;
  hist[base + 2] = excl + h0 + h1;
  hist[base + 3] = excl + h0 + h1 + h2;
  __syncthreads();
  for (int i = tid; i < 1024; i += 256) {
    int k = v[i];
    k = (k == 0) ? 1023 : (k - 1);
    int pos = atomicAdd(&hist[k], 1);
    perm[bh * 1024 + pos] = (u16)i;
  }
}

// ---------------- C[M,N] = A[M,K] * B[N,K]^T  (bf16 in, OUTT out) -------------
template <typename OUTT>
__global__ __launch_bounds__(256) void gemm_bt(const u16* __restrict__ A,
                                               const u16* __restrict__ Bw,
                                               OUTT* __restrict__ C,
                                               long za, long zb, long zc) {
  __shared__ u16 As[128 * 64];
  __shared__ u16 Bs[128 * 64];
  A += (long)blockIdx.z * za;
  Bw += (long)blockIdx.z * zb;
  C += (long)blockIdx.z * zc;
  const int tid = threadIdx.x;
  const int lane = tid & 63;
  const int l15 = lane & 15, lg = lane >> 4;
  const int wid = tid >> 6;
  const int wm = wid >> 1, wn = wid & 1;
  const long mbase = (long)blockIdx.y * 128;
  const long nbase = (long)blockIdx.x * 128;

  const u16* ap = A + (mbase + (tid >> 3)) * 1024 + (tid & 7) * 8;
  const u16* bp = Bw + (nbase + (tid >> 3)) * 1024 + (tid & 7) * 8;

  v4f acc[4][4] = {};

  for (int kt = 0; kt < 16; ++kt) {
    __syncthreads();
#pragma unroll
    for (int j = 0; j < 4; ++j) {
      gload_lds16(ap + kt * 64 + j * 32 * 1024, &As[(tid + 256 * j) * 8]);
      gload_lds16(bp + kt * 64 + j * 32 * 1024, &Bs[(tid + 256 * j) * 8]);
    }
    __syncthreads();
#pragma unroll
    for (int kk = 0; kk < 2; ++kk) {
      v8s a[4], b[4];
#pragma unroll
      for (int i = 0; i < 4; ++i)
        a[i] = *(const v8s*)&As[(wm * 64 + i * 16 + l15) * 64 + kk * 32 + lg * 8];
#pragma unroll
      for (int i = 0; i < 4; ++i)
        b[i] = *(const v8s*)&Bs[(wn * 64 + i * 16 + l15) * 64 + kk * 32 + lg * 8];
#pragma unroll
      for (int mi = 0; mi < 4; ++mi)
#pragma unroll
        for (int nj = 0; nj < 4; ++nj)
          acc[mi][nj] = __builtin_amdgcn_mfma_f32_16x16x32_bf16(a[mi], b[nj], acc[mi][nj], 0, 0, 0);
    }
  }
#pragma unroll
  for (int mi = 0; mi < 4; ++mi) {
#pragma unroll
    for (int r = 0; r < 4; ++r) {
      long row = mbase + wm * 64 + mi * 16 + lg * 4 + r;
#pragma unroll
      for (int nj = 0; nj < 4; ++nj) {
        long col = nbase + wn * 64 + nj * 16 + l15;
        if constexpr (__is_same(OUTT, float))
          C[row * 1024 + col] = acc[mi][nj][r];
        else
          C[row * 1024 + col] = f2b(acc[mi][nj][r]);
      }
    }
  }
}

// ---------------- fused masked attention, split-K, restructured skeleton ------
// grid (32, 64). K is read DIRECTLY from global inside QKT (B-fragment of
// 16x16x32 mfma is a contiguous v8s of a K row; 4 lg-lanes at fixed l15 form
// one 64B line -> coalesced, L2-hot across the 4 waves). V double-buffered in
// LDS -> ONE barrier per tile, placed after softmax so QKT+SM hide the Vt
// commits. WAR safety: lgkmcnt(0) before the barrier drains each wave's PV
// reads of tile t before anyone passes barrier t+1; commits to that buffer
// happen after barrier t+1.
__global__ __launch_bounds__(256) void attn_kern(const u16* __restrict__ qb,
                                                 const u16* __restrict__ kb,
                                                 const u16* __restrict__ vb,
                                                 const int* __restrict__ valid,
                                                 const u16* __restrict__ perm,
                                                 u16* __restrict__ partO,
                                                 float* __restrict__ partM,
                                                 float* __restrict__ partL) {
  __shared__ u16 Vt[2][64 * 72];   // [buf][hd][key], transposed for PV B-operand
  __shared__ u16 Ps[4][16 * 72];   // per-wave P tile [q][key]

  const int tid = threadIdx.x;
  const int lane = tid & 63;
  const int wid = tid >> 6;
  const int l15 = lane & 15, lg = lane >> 4;
  const int bh = blockIdx.y;
  const int b = bh >> 4, h = bh & 15;
  const long headoff = ((long)b * LL) * DD + h * 64;
  const int xx = blockIdx.x;
  const int gq = 15 - (xx >> 1);
  const int ch = xx & 1;
  const u16* pblk = perm + bh * 1024 + gq * 64;

  const int lastv = valid[bh * LL + pblk[63]];
  const int ntiles = ((lastv == 0 ? LL : lastv) + 63) >> 6;
  const int kt0 = ch * 8;
  const int kt1 = min(ntiles, kt0 + 8);
  if (kt0 >= kt1) return;
  const int slot = (bh * 16 + gq) * 2 + ch;

  const u16* pp = pblk + wid * 16;

  // Q A-fragments live in registers for the whole kernel
  const int qrowA = pp[l15];
  v8s qf[2];
#pragma unroll
  for (int ks = 0; ks < 2; ++ks)
    qf[ks] = *(const v8s*)(qb + headoff + (long)qrowA * DD + ks * 32 + lg * 8);

  int vraw[4];
#pragma unroll
  for (int r = 0; r < 4; ++r) vraw[r] = valid[bh * LL + pp[lg * 4 + r]];

  float mrow[4], lrow[4];
  v4f oacc[4] = {};
#pragma unroll
  for (int r = 0; r < 4; ++r) { mrow[r] = -1e30f; lrow[r] = 0.0f; }

  const int kk = tid & 63;   // staging: key row
  const int qtr = tid >> 6;  // staging: 16-wide hd quarter
  const long stagebase = headoff + (long)kk * DD + qtr * 16;
  const u16* kbh = kb + headoff;

  // prologue: issue first tile's V loads (reg staging, write-late)
  v8s rv0 = *(const v8s*)(vb + stagebase + (long)kt0 * 64 * DD);
  v8s rv1 = *(const v8s*)(vb + stagebase + (long)kt0 * 64 * DD + 8);

  for (int kt = kt0; kt < kt1; ++kt) {
    const int cur = kt & 1;
    // commit staged V -> Vt[cur] (scalar transpose; compiler waits rv* counted)
    {
      v8u u0 = __builtin_bit_cast(v8u, rv0);
      v8u u1 = __builtin_bit_cast(v8u, rv1);
#pragma unroll
      for (int j = 0; j < 8; ++j) Vt[cur][(qtr * 16 + j) * 72 + kk] = u0[j];
#pragma unroll
      for (int j = 0; j < 8; ++j) Vt[cur][(qtr * 16 + 8 + j) * 72 + kk] = u1[j];
    }

    // QKT with K direct from global; K loads issued BEFORE the V prefetch so
    // counted vmcnt on K-use keeps the V loads in flight across the tile.
    const u16* ktb = kbh + (long)(kt * 64) * DD;
    v8s kf[4][2];
#pragma unroll
    for (int t = 0; t < 4; ++t)
#pragma unroll
      for (int ks = 0; ks < 2; ++ks)
        kf[t][ks] = *(const v8s*)(ktb + (long)(t * 16 + l15) * DD + ks * 32 + lg * 8);

    // prefetch next tile's V
    if (kt + 1 < kt1) {
      const long noff = stagebase + (long)(kt + 1) * 64 * DD;
      rv0 = *(const v8s*)(vb + noff);
      rv1 = *(const v8s*)(vb + noff + 8);
    }

    v4f s[4];
    __builtin_amdgcn_s_setprio(1);
#pragma unroll
    for (int t = 0; t < 4; ++t) {
      v4f z = {};
#pragma unroll
      for (int ks = 0; ks < 2; ++ks)
        z = __builtin_amdgcn_mfma_f32_16x16x32_bf16(qf[ks], kf[t][ks], z, 0, 0, 0);
      s[t] = z;
    }
    __builtin_amdgcn_s_setprio(0);

    // scale into log2 domain + mask (ref semantics: -1e6, col < valid_raw)
    const float SC = 0.18033688f;  // (1/8) * log2(e)
    const int colbase = kt * 64 + l15;
#pragma unroll
    for (int t = 0; t < 4; ++t)
#pragma unroll
      for (int r = 0; r < 4; ++r) {
        float val = s[t][r] * SC;
        s[t][r] = (colbase + t * 16 < vraw[r]) ? val : -1e6f;
      }

    // online softmax (log2 domain) with defer-max
    float pm[4];
#pragma unroll
    for (int r = 0; r < 4; ++r)
      pm[r] = fmaxf(fmaxf(s[0][r], s[1][r]), fmaxf(s[2][r], s[3][r]));
#pragma unroll
    for (int d = 1; d < 16; d <<= 1)
#pragma unroll
      for (int r = 0; r < 4; ++r) pm[r] = fmaxf(pm[r], __shfl_xor(pm[r], d));

    bool sk = true;
#pragma unroll
    for (int r = 0; r < 4; ++r) sk = sk && (pm[r] <= mrow[r] + 11.0f);
    if (!__all(sk)) {
#pragma unroll
      for (int r = 0; r < 4; ++r) {
        float mn = fmaxf(mrow[r], pm[r]);
        float sc = __builtin_amdgcn_exp2f(mrow[r] - mn);
        mrow[r] = mn;
        lrow[r] *= sc;
#pragma unroll
        for (int t = 0; t < 4; ++t) oacc[t][r] *= sc;
      }
    }
    float rs[4] = {0.f, 0.f, 0.f, 0.f};
#pragma unroll
    for (int t = 0; t < 4; ++t)
#pragma unroll
      for (int r = 0; r < 4; ++r) {
        float p = __builtin_amdgcn_exp2f(s[t][r] - mrow[r]);
        s[t][r] = p;
        rs[r] += p;
      }
#pragma unroll
    for (int d = 1; d < 16; d <<= 1)
#pragma unroll
      for (int r = 0; r < 4; ++r) rs[r] += __shfl_xor(rs[r], d);
#pragma unroll
    for (int r = 0; r < 4; ++r) lrow[r] += rs[r];

    // ---- single barrier per tile: Vt[cur] visible to all waves; also drains
    // this wave's previous-tile PV reads (WAR safety for buffer reuse).
    asm volatile("s_waitcnt lgkmcnt(0)" ::: "memory");
    __builtin_amdgcn_sched_barrier(0);
    __builtin_amdgcn_s_barrier();
    __builtin_amdgcn_sched_barrier(0);

    // P -> bf16 -> per-wave LDS, then consume as MFMA A-operand
#pragma unroll
    for (int t = 0; t < 4; ++t)
#pragma unroll
      for (int r = 0; r < 4; ++r)
        Ps[wid][(lg * 4 + r) * 72 + t * 16 + l15] = f2b(s[t][r]);

    asm volatile("s_waitcnt lgkmcnt(0)" ::: "memory");
    __builtin_amdgcn_sched_barrier(0);

    __builtin_amdgcn_s_setprio(1);
#pragma unroll
    for (int ks = 0; ks < 2; ++ks) {
      v8s pa = *(const v8s*)&Ps[wid][l15 * 72 + ks * 32 + lg * 8];
#pragma unroll
      for (int t = 0; t < 4; ++t) {
        v8s vf = *(const v8s*)&Vt[cur][(t * 16 + l15) * 72 + ks * 32 + lg * 8];
        oacc[t] = __builtin_amdgcn_mfma_f32_16x16x32_bf16(pa, vf, oacc[t], 0, 0, 0);
      }
    }
    __builtin_amdgcn_s_setprio(0);
  }

  // epilogue: write UNNORMALIZED partials (sorted-row order); merge normalizes
  u16* po = partO + (long)slot * 4096;
  float* pmv = partM + slot * 64;
  float* plv = partL + slot * 64;
#pragma unroll
  for (int r = 0; r < 4; ++r) {
    int p = wid * 16 + lg * 4 + r;
    pmv[p] = mrow[r];
    plv[p] = lrow[r];
#pragma unroll
    for (int t = 0; t < 4; ++t)
      po[p * 64 + t * 16 + l15] = f2b(oacc[t][r]);
  }
}

// ---------------- merge the (up to 2) chunk partials per (bh, group) ----------
__global__ __launch_bounds__(256) void merge_kern(const int* __restrict__ valid,
                                                  const u16* __restrict__ perm,
                                                  const u16* __restrict__ partO,
                                                  const float* __restrict__ partM,
                                                  const float* __restrict__ partL,
                                                  u16* __restrict__ ob) {
  const int g = blockIdx.x, bh = blockIdx.y;
  const int b = bh >> 4, h = bh & 15;
  const u16* pblk = perm + bh * 1024 + g * 64;
  const int lastv = valid[bh * LL + pblk[63]];
  const int ntiles = ((lastv == 0 ? LL : lastv) + 63) >> 6;
  const bool has1 = ntiles > 8;
  const int p = threadIdx.x >> 2;
  const int q4 = (threadIdx.x & 3) * 16;
  const int s0 = (bh * 16 + g) * 2;

  float m0 = partM[s0 * 64 + p], l0 = partL[s0 * 64 + p];
  float w0 = 1.0f, w1 = 0.0f, L = l0;
  if (has1) {
    float m1 = partM[(s0 + 1) * 64 + p], l1 = partL[(s0 + 1) * 64 + p];
    float M = fmaxf(m0, m1);
    w0 = __builtin_amdgcn_exp2f(m0 - M);
    w1 = __builtin_amdgcn_exp2f(m1 - M);
    L = l0 * w0 + l1 * w1;
  }
  const float inv = 1.0f / L;

  const u16* po0 = partO + (long)s0 * 4096 + p * 64 + q4;
  float acc[16];
  {
    v8u x0 = *(const v8u*)po0;
    v8u x1 = *(const v8u*)(po0 + 8);
#pragma unroll
    for (int j = 0; j < 8; ++j) acc[j] = b2f(x0[j]) * w0;
#pragma unroll
    for (int j = 0; j < 8; ++j) acc[8 + j] = b2f(x1[j]) * w0;
  }
  if (has1) {
    const u16* po1 = po0 + 4096;
    v8u y0 = *(const v8u*)po1;
    v8u y1 = *(const v8u*)(po1 + 8);
#pragma unroll
    for (int j = 0; j < 8; ++j) acc[j] += b2f(y0[j]) * w1;
#pragma unroll
    for (int j = 0; j < 8; ++j) acc[8 + j] += b2f(y1[j]) * w1;
  }
  const int orow = pblk[p];
  u16* dst = ob + ((long)b * LL + orow) * DD + h * 64 + q4;
#pragma unroll
  for (int j = 0; j < 16; ++j) dst[j] = f2b(acc[j] * inv);
}

// ---------------- launch ------------------------------------------------------
extern "C" void kernel_launch(void* const* d_in, const int* in_sizes, int n_in,
                              void* d_out, int out_size, void* d_ws, size_t ws_size,
                              hipStream_t stream) {
  const float* Q = (const float*)d_in[0];
  const float* K = (const float*)d_in[1];
  const float* V = (const float*)d_in[2];
  const int* valid = (const int*)d_in[3];
  const float* Wq = (const float*)d_in[4];
  const float* Wk = (const float*)d_in[5];
  const float* Wv = (const float*)d_in[6];
  const float* Wo = (const float*)d_in[7];
  float* out = (float*)d_out;

  u16* ws = (u16*)d_ws;
  const long MK = 4096L * 1024;
  const long NK = 1024L * 1024;
  u16* qkvb = ws;
  u16* wqkv = qkvb + 3 * MK;
  u16* wo = wqkv + 3 * NK;
  u16* proj = wo + NK;
  u16* ob = proj + 3 * MK;
  u16* perm = wqkv;                              // dead after proj GEMM
  u16* partO = qkvb;                             // dead after proj GEMM
  float* partM = (float*)(qkvb + 2048L * 4096);
  float* partL = partM + 2048L * 64;

  cvt3<<<dim3(2048, 3), 256, 0, stream>>>(Q, K, V, qkvb, (int)(MK / 8), MK);
  cvt3<<<dim3(512, 3), 256, 0, stream>>>(Wq, Wk, Wv, wqkv, (int)(NK / 8), NK);
  cvt3<<<dim3(512, 1), 256, 0, stream>>>(Wo, Wo, Wo, wo, (int)(NK / 8), 0);

  gemm_bt<u16><<<dim3(8, 32, 3), 256, 0, stream>>>(qkvb, wqkv, proj, MK, NK, MK);
  sortperm<<<64, 256, 0, stream>>>(valid, perm);
  attn_kern<<<dim3(32, 64), 256, 0, stream>>>(proj, proj + MK, proj + 2 * MK, valid,
                                              perm, partO, partM, partL);
  merge_kern<<<dim3(16, 64), 256, 0, stream>>>(valid, perm, partO, partM, partL, ob);
  gemm_bt<float><<<dim3(8, 32, 1), 256, 0, stream>>>(ob, wo, out, 0, 0, 0);
}

// Round 15
// 153.638 us; speedup vs baseline: 7.1012x; 1.1654x over previous
//
#include <hip/hip_runtime.h>
#include <hip/hip_bf16.h>

typedef short v8s __attribute__((ext_vector_type(8)));
typedef unsigned short v8u __attribute__((ext_vector_type(8)));
typedef float v4f __attribute__((ext_vector_type(4)));
typedef unsigned short u16;

#define LL 1024
#define DD 1024

static __device__ __forceinline__ u16 f2b(float x) {
  __hip_bfloat16 h = __float2bfloat16(x);
  return __builtin_bit_cast(u16, h);
}
static __device__ __forceinline__ float b2f(u16 u) {
  unsigned int x = ((unsigned int)u) << 16;
  return __builtin_bit_cast(float, x);
}

static __device__ __forceinline__ void gload_lds16(const u16* g, u16* l) {
  __builtin_amdgcn_global_load_lds((const __attribute__((address_space(1))) void*)g,
                                   (__attribute__((address_space(3))) void*)l, 16, 0, 0);
}

// ---------------- f32 -> bf16 conversion, ALL 7 tensors in one launch --------
// y<3: Q,K,V (n8=MK/8, dst=ws+y*MK). y>=3: Wq,Wk,Wv,Wo (n8=NK/8, contiguous
// after qkv region). Extra blocks for the small tensors early-exit.
__global__ __launch_bounds__(256) void cvt7(const float* __restrict__ p0,
                                            const float* __restrict__ p1,
                                            const float* __restrict__ p2,
                                            const float* __restrict__ p3,
                                            const float* __restrict__ p4,
                                            const float* __restrict__ p5,
                                            const float* __restrict__ p6,
                                            u16* __restrict__ ws) {
  const long MK = 4096L * 1024, NK = 1024L * 1024;
  const int y = blockIdx.y;
  const float* srcs[7] = {p0, p1, p2, p3, p4, p5, p6};
  const float* src = srcs[y];
  u16* dst = (y < 3) ? ws + (long)y * MK : ws + 3 * MK + (long)(y - 3) * NK;
  const int n8 = (y < 3) ? (int)(MK / 8) : (int)(NK / 8);
  int i = blockIdx.x * 256 + threadIdx.x;
  if (i >= n8) return;
  const float4* p = (const float4*)src + (long)i * 2;
  float4 a = p[0], b = p[1];
  v8u r;
  r[0] = f2b(a.x); r[1] = f2b(a.y); r[2] = f2b(a.z); r[3] = f2b(a.w);
  r[4] = f2b(b.x); r[5] = f2b(b.y); r[6] = f2b(b.z); r[7] = f2b(b.w);
  *((v8u*)dst + i) = r;
}

// ---------------- per-head counting sort of q-rows by effective valid len ----
__global__ __launch_bounds__(256) void sortperm(const int* __restrict__ valid,
                                                u16* __restrict__ perm) {
  __shared__ int hist[1024];
  __shared__ int wsum[4];
  const int bh = blockIdx.x;
  const int tid = threadIdx.x;
  const int* v = valid + bh * 1024;
  for (int i = tid; i < 1024; i += 256) hist[i] = 0;
  __syncthreads();
  for (int i = tid; i < 1024; i += 256) {
    int k = v[i];
    k = (k == 0) ? 1023 : (k - 1);  // bin = eff-1
    atomicAdd(&hist[k], 1);
  }
  __syncthreads();
  const int base = tid * 4;
  int h0 = hist[base], h1 = hist[base + 1], h2 = hist[base + 2], h3 = hist[base + 3];
  int local = h0 + h1 + h2 + h3;
  const int lane = tid & 63, w = tid >> 6;
  int scan = local;
#pragma unroll
  for (int d = 1; d < 64; d <<= 1) {
    int t = __shfl_up(scan, d);
    if (lane >= d) scan += t;
  }
  if (lane == 63) wsum[w] = scan;
  __syncthreads();
  int woff = 0;
  for (int i = 0; i < w; ++i) woff += wsum[i];
  int excl = woff + scan - local;
  hist[base] = excl;
  hist[base + 1] = excl + h0;
  hist[base + 2] = excl + h0 + h1;
  hist[base + 3] = excl + h0 + h1 + h2;
  __syncthreads();
  for (int i = tid; i < 1024; i += 256) {
    int k = v[i];
    k = (k == 0) ? 1023 : (k - 1);
    int pos = atomicAdd(&hist[k], 1);
    perm[bh * 1024 + pos] = (u16)i;
  }
}

// ---------------- C[M,N] = A[M,K] * B[N,K]^T  (bf16 in, OUTT out) -------------
template <typename OUTT>
__global__ __launch_bounds__(256) void gemm_bt(const u16* __restrict__ A,
                                               const u16* __restrict__ Bw,
                                               OUTT* __restrict__ C,
                                               long za, long zb, long zc) {
  __shared__ u16 As[128 * 64];
  __shared__ u16 Bs[128 * 64];
  A += (long)blockIdx.z * za;
  Bw += (long)blockIdx.z * zb;
  C += (long)blockIdx.z * zc;
  const int tid = threadIdx.x;
  const int lane = tid & 63;
  const int l15 = lane & 15, lg = lane >> 4;
  const int wid = tid >> 6;
  const int wm = wid >> 1, wn = wid & 1;
  const long mbase = (long)blockIdx.y * 128;
  const long nbase = (long)blockIdx.x * 128;

  const u16* ap = A + (mbase + (tid >> 3)) * 1024 + (tid & 7) * 8;
  const u16* bp = Bw + (nbase + (tid >> 3)) * 1024 + (tid & 7) * 8;

  v4f acc[4][4] = {};

  for (int kt = 0; kt < 16; ++kt) {
    __syncthreads();
#pragma unroll
    for (int j = 0; j < 4; ++j) {
      gload_lds16(ap + kt * 64 + j * 32 * 1024, &As[(tid + 256 * j) * 8]);
      gload_lds16(bp + kt * 64 + j * 32 * 1024, &Bs[(tid + 256 * j) * 8]);
    }
    __syncthreads();
#pragma unroll
    for (int kk = 0; kk < 2; ++kk) {
      v8s a[4], b[4];
#pragma unroll
      for (int i = 0; i < 4; ++i)
        a[i] = *(const v8s*)&As[(wm * 64 + i * 16 + l15) * 64 + kk * 32 + lg * 8];
#pragma unroll
      for (int i = 0; i < 4; ++i)
        b[i] = *(const v8s*)&Bs[(wn * 64 + i * 16 + l15) * 64 + kk * 32 + lg * 8];
#pragma unroll
      for (int mi = 0; mi < 4; ++mi)
#pragma unroll
        for (int nj = 0; nj < 4; ++nj)
          acc[mi][nj] = __builtin_amdgcn_mfma_f32_16x16x32_bf16(a[mi], b[nj], acc[mi][nj], 0, 0, 0);
    }
  }
#pragma unroll
  for (int mi = 0; mi < 4; ++mi) {
#pragma unroll
    for (int r = 0; r < 4; ++r) {
      long row = mbase + wm * 64 + mi * 16 + lg * 4 + r;
#pragma unroll
      for (int nj = 0; nj < 4; ++nj) {
        long col = nbase + wn * 64 + nj * 16 + l15;
        if constexpr (__is_same(OUTT, float))
          C[row * 1024 + col] = acc[mi][nj][r];
        else
          C[row * 1024 + col] = f2b(acc[mi][nj][r]);
      }
    }
  }
}

// ---------------- fused masked attention, split-K (round-10 best: 67.7 us) ----
// grid (32, 64): x -> (g = 15-(x>>1), chunk c = x&1), heavy groups first.
// Chunk c covers tiles [c*8, min(ntiles,(c+1)*8)). Unnormalized flash partials
// (O bf16, m/l f32, log2 domain) per slot; merge_kern combines.
__global__ __launch_bounds__(256) void attn_kern(const u16* __restrict__ qb,
                                                 const u16* __restrict__ kb,
                                                 const u16* __restrict__ vb,
                                                 const int* __restrict__ valid,
                                                 const u16* __restrict__ perm,
                                                 u16* __restrict__ partO,
                                                 float* __restrict__ partM,
                                                 float* __restrict__ partL) {
  __shared__ u16 Ks[64 * 72];       // [key][hd], +8 pad -> no 16-way conflict
  __shared__ u16 Vt[64 * 72];       // [hd][key], transposed for PV B-operand
  __shared__ u16 Ps[4][16 * 72];    // per-wave P tile [q][key]

  const int tid = threadIdx.x;
  const int lane = tid & 63;
  const int wid = tid >> 6;
  const int l15 = lane & 15, lg = lane >> 4;
  const int bh = blockIdx.y;
  const int b = bh >> 4, h = bh & 15;
  const long headoff = ((long)b * LL) * DD + h * 64;
  const int xx = blockIdx.x;
  const int gq = 15 - (xx >> 1);   // heaviest sorted group dispatched first
  const int ch = xx & 1;
  const u16* pblk = perm + bh * 1024 + gq * 64;

  const int lastv = valid[bh * LL + pblk[63]];
  const int ntiles = ((lastv == 0 ? LL : lastv) + 63) >> 6;
  const int kt0 = ch * 8;
  const int kt1 = min(ntiles, kt0 + 8);
  if (kt0 >= kt1) return;  // chunk 1 absent for light groups
  const int slot = (bh * 16 + gq) * 2 + ch;

  const u16* pp = pblk + wid * 16;

  // Q A-fragments (rows via perm) live in registers for the whole kernel
  const int qrowA = pp[l15];
  v8s qf[2];
#pragma unroll
  for (int ks = 0; ks < 2; ++ks)
    qf[ks] = *(const v8s*)(qb + headoff + (long)qrowA * DD + ks * 32 + lg * 8);

  // per-lane C-frag rows (lg*4+r): raw valid for masking
  int vraw[4];
#pragma unroll
  for (int r = 0; r < 4; ++r) vraw[r] = valid[bh * LL + pp[lg * 4 + r]];

  float mrow[4], lrow[4];
  v4f oacc[4] = {};
#pragma unroll
  for (int r = 0; r < 4; ++r) { mrow[r] = -1e30f; lrow[r] = 0.0f; }

  const int kk = tid & 63;   // staging: key row
  const int qtr = tid >> 6;  // staging: 16-wide hd quarter
  const long stagebase = headoff + (long)kk * DD + qtr * 16;

  // prologue: issue first tile's K/V loads (reg staging, write-late)
  v8s rk0 = *(const v8s*)(kb + stagebase + (long)kt0 * 64 * DD);
  v8s rk1 = *(const v8s*)(kb + stagebase + (long)kt0 * 64 * DD + 8);
  v8s rv0 = *(const v8s*)(vb + stagebase + (long)kt0 * 64 * DD);
  v8s rv1 = *(const v8s*)(vb + stagebase + (long)kt0 * 64 * DD + 8);

  for (int kt = kt0; kt < kt1; ++kt) {
    // ---- barrier A (WAR guard): raw s_barrier, no vmcnt drain.
    __builtin_amdgcn_sched_barrier(0);
    __builtin_amdgcn_s_barrier();
    __builtin_amdgcn_sched_barrier(0);

    // commit staged regs -> LDS (compiler inserts COUNTED vmcnt for rk*/rv*)
    *(v8s*)&Ks[kk * 72 + qtr * 16] = rk0;
    *(v8s*)&Ks[kk * 72 + qtr * 16 + 8] = rk1;
    {
      v8u u0 = __builtin_bit_cast(v8u, rv0);
      v8u u1 = __builtin_bit_cast(v8u, rv1);
#pragma unroll
      for (int j = 0; j < 8; ++j) Vt[(qtr * 16 + j) * 72 + kk] = u0[j];
#pragma unroll
      for (int j = 0; j < 8; ++j) Vt[(qtr * 16 + 8 + j) * 72 + kk] = u1[j];
    }
    // prefetch next tile's K/V; stays in flight across barrier B + compute
    if (kt + 1 < kt1) {
      const long noff = stagebase + (long)(kt + 1) * 64 * DD;
      rk0 = *(const v8s*)(kb + noff);
      rk1 = *(const v8s*)(kb + noff + 8);
      rv0 = *(const v8s*)(vb + noff);
      rv1 = *(const v8s*)(vb + noff + 8);
    }
    // ---- barrier B: ds_writes visible; vmcnt NOT drained.
    asm volatile("s_waitcnt lgkmcnt(0)" ::: "memory");
    __builtin_amdgcn_sched_barrier(0);
    __builtin_amdgcn_s_barrier();
    __builtin_amdgcn_sched_barrier(0);

    // S = Q K^T for 16 q rows x 64 keys
    v4f s[4];
    __builtin_amdgcn_s_setprio(1);
#pragma unroll
    for (int t = 0; t < 4; ++t) {
      v4f z = {};
#pragma unroll
      for (int ks = 0; ks < 2; ++ks) {
        v8s kf = *(const v8s*)&Ks[(t * 16 + l15) * 72 + ks * 32 + lg * 8];
        z = __builtin_amdgcn_mfma_f32_16x16x32_bf16(qf[ks], kf, z, 0, 0, 0);
      }
      s[t] = z;
    }
    __builtin_amdgcn_s_setprio(0);

    // scale into log2 domain + mask (ref semantics: -1e6, col < valid_raw)
    const float SC = 0.18033688f;  // (1/8) * log2(e)
    const int colbase = kt * 64 + l15;
#pragma unroll
    for (int t = 0; t < 4; ++t)
#pragma unroll
      for (int r = 0; r < 4; ++r) {
        float val = s[t][r] * SC;
        s[t][r] = (colbase + t * 16 < vraw[r]) ? val : -1e6f;
      }

    // online softmax (log2 domain) with defer-max: rescale only if max grew >11
    float pm[4];
#pragma unroll
    for (int r = 0; r < 4; ++r)
      pm[r] = fmaxf(fmaxf(s[0][r], s[1][r]), fmaxf(s[2][r], s[3][r]));
#pragma unroll
    for (int d = 1; d < 16; d <<= 1)
#pragma unroll
      for (int r = 0; r < 4; ++r) pm[r] = fmaxf(pm[r], __shfl_xor(pm[r], d));

    bool sk = true;
#pragma unroll
    for (int r = 0; r < 4; ++r) sk = sk && (pm[r] <= mrow[r] + 11.0f);
    if (!__all(sk)) {
#pragma unroll
      for (int r = 0; r < 4; ++r) {
        float mn = fmaxf(mrow[r], pm[r]);
        float sc = __builtin_amdgcn_exp2f(mrow[r] - mn);
        mrow[r] = mn;
        lrow[r] *= sc;
#pragma unroll
        for (int t = 0; t < 4; ++t) oacc[t][r] *= sc;
      }
    }
    float rs[4] = {0.f, 0.f, 0.f, 0.f};
#pragma unroll
    for (int t = 0; t < 4; ++t)
#pragma unroll
      for (int r = 0; r < 4; ++r) {
        float p = __builtin_amdgcn_exp2f(s[t][r] - mrow[r]);
        s[t][r] = p;
        rs[r] += p;
      }
#pragma unroll
    for (int d = 1; d < 16; d <<= 1)
#pragma unroll
      for (int r = 0; r < 4; ++r) rs[r] += __shfl_xor(rs[r], d);
#pragma unroll
    for (int r = 0; r < 4; ++r) lrow[r] += rs[r];

    // P -> bf16 -> per-wave LDS, then consume as MFMA A-operand
#pragma unroll
    for (int t = 0; t < 4; ++t)
#pragma unroll
      for (int r = 0; r < 4; ++r)
        Ps[wid][(lg * 4 + r) * 72 + t * 16 + l15] = f2b(s[t][r]);

    asm volatile("s_waitcnt lgkmcnt(0)" ::: "memory");
    __builtin_amdgcn_sched_barrier(0);

    __builtin_amdgcn_s_setprio(1);
#pragma unroll
    for (int ks = 0; ks < 2; ++ks) {
      v8s pa = *(const v8s*)&Ps[wid][l15 * 72 + ks * 32 + lg * 8];
#pragma unroll
      for (int t = 0; t < 4; ++t) {
        v8s vf = *(const v8s*)&Vt[(t * 16 + l15) * 72 + ks * 32 + lg * 8];
        oacc[t] = __builtin_amdgcn_mfma_f32_16x16x32_bf16(pa, vf, oacc[t], 0, 0, 0);
      }
    }
    __builtin_amdgcn_s_setprio(0);
  }

  // epilogue: write UNNORMALIZED partials (sorted-row order); merge normalizes
  u16* po = partO + (long)slot * 4096;
  float* pmv = partM + slot * 64;
  float* plv = partL + slot * 64;
#pragma unroll
  for (int r = 0; r < 4; ++r) {
    int p = wid * 16 + lg * 4 + r;
    pmv[p] = mrow[r];
    plv[p] = lrow[r];
#pragma unroll
    for (int t = 0; t < 4; ++t)
      po[p * 64 + t * 16 + l15] = f2b(oacc[t][r]);
  }
}

// ---------------- merge the (up to 2) chunk partials per (bh, group) ----------
__global__ __launch_bounds__(256) void merge_kern(const int* __restrict__ valid,
                                                  const u16* __restrict__ perm,
                                                  const u16* __restrict__ partO,
                                                  const float* __restrict__ partM,
                                                  const float* __restrict__ partL,
                                                  u16* __restrict__ ob) {
  const int g = blockIdx.x, bh = blockIdx.y;
  const int b = bh >> 4, h = bh & 15;
  const u16* pblk = perm + bh * 1024 + g * 64;
  const int lastv = valid[bh * LL + pblk[63]];
  const int ntiles = ((lastv == 0 ? LL : lastv) + 63) >> 6;
  const bool has1 = ntiles > 8;
  const int p = threadIdx.x >> 2;
  const int q4 = (threadIdx.x & 3) * 16;
  const int s0 = (bh * 16 + g) * 2;

  float m0 = partM[s0 * 64 + p], l0 = partL[s0 * 64 + p];
  float w0 = 1.0f, w1 = 0.0f, L = l0;
  if (has1) {
    float m1 = partM[(s0 + 1) * 64 + p], l1 = partL[(s0 + 1) * 64 + p];
    float M = fmaxf(m0, m1);
    w0 = __builtin_amdgcn_exp2f(m0 - M);
    w1 = __builtin_amdgcn_exp2f(m1 - M);
    L = l0 * w0 + l1 * w1;
  }
  const float inv = 1.0f / L;

  const u16* po0 = partO + (long)s0 * 4096 + p * 64 + q4;
  float acc[16];
  {
    v8u x0 = *(const v8u*)po0;
    v8u x1 = *(const v8u*)(po0 + 8);
#pragma unroll
    for (int j = 0; j < 8; ++j) acc[j] = b2f(x0[j]) * w0;
#pragma unroll
    for (int j = 0; j < 8; ++j) acc[8 + j] = b2f(x1[j]) * w0;
  }
  if (has1) {
    const u16* po1 = po0 + 4096;
    v8u y0 = *(const v8u*)po1;
    v8u y1 = *(const v8u*)(po1 + 8);
#pragma unroll
    for (int j = 0; j < 8; ++j) acc[j] += b2f(y0[j]) * w1;
#pragma unroll
    for (int j = 0; j < 8; ++j) acc[8 + j] += b2f(y1[j]) * w1;
  }
  const int orow = pblk[p];
  u16* dst = ob + ((long)b * LL + orow) * DD + h * 64 + q4;
#pragma unroll
  for (int j = 0; j < 16; ++j) dst[j] = f2b(acc[j] * inv);
}

// ---------------- launch ------------------------------------------------------
extern "C" void kernel_launch(void* const* d_in, const int* in_sizes, int n_in,
                              void* d_out, int out_size, void* d_ws, size_t ws_size,
                              hipStream_t stream) {
  const float* Q = (const float*)d_in[0];
  const float* K = (const float*)d_in[1];
  const float* V = (const float*)d_in[2];
  const int* valid = (const int*)d_in[3];
  const float* Wq = (const float*)d_in[4];
  const float* Wk = (const float*)d_in[5];
  const float* Wv = (const float*)d_in[6];
  const float* Wo = (const float*)d_in[7];
  float* out = (float*)d_out;

  u16* ws = (u16*)d_ws;
  const long MK = 4096L * 1024;
  const long NK = 1024L * 1024;
  u16* qkvb = ws;              // bf16 Q,K,V  3*MK (dead after proj GEMM)
  u16* wqkv = qkvb + 3 * MK;   // bf16 Wq,Wk,Wv 3*NK (dead after proj GEMM)
  u16* wo = wqkv + 3 * NK;     // bf16 Wo NK
  u16* proj = wo + NK;         // q,k,v projections 3*MK
  u16* ob = proj + 3 * MK;     // attention output MK
  u16* perm = wqkv;                              // reuses dead wqkv
  u16* partO = qkvb;                             // reuses dead qkvb
  float* partM = (float*)(qkvb + 2048L * 4096);
  float* partL = partM + 2048L * 64;

  cvt7<<<dim3(2048, 7), 256, 0, stream>>>(Q, K, V, Wq, Wk, Wv, Wo, ws);

  gemm_bt<u16><<<dim3(8, 32, 3), 256, 0, stream>>>(qkvb, wqkv, proj, MK, NK, MK);
  sortperm<<<64, 256, 0, stream>>>(valid, perm);
  attn_kern<<<dim3(32, 64), 256, 0, stream>>>(proj, proj + MK, proj + 2 * MK, valid,
                                              perm, partO, partM, partL);
  merge_kern<<<dim3(16, 64), 256, 0, stream>>>(valid, perm, partO, partM, partL, ob);
  gemm_bt<float><<<dim3(8, 32, 1), 256, 0, stream>>>(ob, wo, out, 0, 0, 0);
}

// Round 16
// 141.199 us; speedup vs baseline: 7.7269x; 1.0881x over previous
//
#include <hip/hip_runtime.h>
#include <hip/hip_bf16.h>

typedef short v8s __attribute__((ext_vector_type(8)));
typedef unsigned short v8u __attribute__((ext_vector_type(8)));
typedef float v4f __attribute__((ext_vector_type(4)));
typedef unsigned short u16;

#define LL 1024
#define DD 1024

static __device__ __forceinline__ u16 f2b(float x) {
  __hip_bfloat16 h = __float2bfloat16(x);
  return __builtin_bit_cast(u16, h);
}
static __device__ __forceinline__ float b2f(u16 u) {
  unsigned int x = ((unsigned int)u) << 16;
  return __builtin_bit_cast(float, x);
}

static __device__ __forceinline__ void gload_lds16(const u16* g, u16* l) {
  __builtin_amdgcn_global_load_lds((const __attribute__((address_space(1))) void*)g,
                                   (__attribute__((address_space(3))) void*)l, 16, 0, 0);
}

// ---------------- f32 -> bf16 conversion, ALL 7 tensors in one launch --------
__global__ __launch_bounds__(256) void cvt7(const float* __restrict__ p0,
                                            const float* __restrict__ p1,
                                            const float* __restrict__ p2,
                                            const float* __restrict__ p3,
                                            const float* __restrict__ p4,
                                            const float* __restrict__ p5,
                                            const float* __restrict__ p6,
                                            u16* __restrict__ ws) {
  const long MK = 4096L * 1024, NK = 1024L * 1024;
  const int y = blockIdx.y;
  const float* srcs[7] = {p0, p1, p2, p3, p4, p5, p6};
  const float* src = srcs[y];
  u16* dst = (y < 3) ? ws + (long)y * MK : ws + 3 * MK + (long)(y - 3) * NK;
  const int n8 = (y < 3) ? (int)(MK / 8) : (int)(NK / 8);
  int i = blockIdx.x * 256 + threadIdx.x;
  if (i >= n8) return;
  const float4* p = (const float4*)src + (long)i * 2;
  float4 a = p[0], b = p[1];
  v8u r;
  r[0] = f2b(a.x); r[1] = f2b(a.y); r[2] = f2b(a.z); r[3] = f2b(a.w);
  r[4] = f2b(b.x); r[5] = f2b(b.y); r[6] = f2b(b.z); r[7] = f2b(b.w);
  *((v8u*)dst + i) = r;
}

// ---------------- per-head counting sort of q-rows by effective valid len ----
__global__ __launch_bounds__(256) void sortperm(const int* __restrict__ valid,
                                                u16* __restrict__ perm) {
  __shared__ int hist[1024];
  __shared__ int wsum[4];
  const int bh = blockIdx.x;
  const int tid = threadIdx.x;
  const int* v = valid + bh * 1024;
  for (int i = tid; i < 1024; i += 256) hist[i] = 0;
  __syncthreads();
  for (int i = tid; i < 1024; i += 256) {
    int k = v[i];
    k = (k == 0) ? 1023 : (k - 1);  // bin = eff-1
    atomicAdd(&hist[k], 1);
  }
  __syncthreads();
  const int base = tid * 4;
  int h0 = hist[base], h1 = hist[base + 1], h2 = hist[base + 2], h3 = hist[base + 3];
  int local = h0 + h1 + h2 + h3;
  const int lane = tid & 63, w = tid >> 6;
  int scan = local;
#pragma unroll
  for (int d = 1; d < 64; d <<= 1) {
    int t = __shfl_up(scan, d);
    if (lane >= d) scan += t;
  }
  if (lane == 63) wsum[w] = scan;
  __syncthreads();
  int woff = 0;
  for (int i = 0; i < w; ++i) woff += wsum[i];
  int excl = woff + scan - local;
  hist[base] = excl;
  hist[base + 1] = excl + h0;
  hist[base + 2] = excl + h0 + h1;
  hist[base + 3] = excl + h0 + h1 + h2;
  __syncthreads();
  for (int i = tid; i < 1024; i += 256) {
    int k = v[i];
    k = (k == 0) ? 1023 : (k - 1);
    int pos = atomicAdd(&hist[k], 1);
    perm[bh * 1024 + pos] = (u16)i;
  }
}

// ---------------- C[M,N] = A[M,K] * B[N,K]^T  (bf16 in, OUTT out) -------------
template <typename OUTT>
__global__ __launch_bounds__(256) void gemm_bt(const u16* __restrict__ A,
                                               const u16* __restrict__ Bw,
                                               OUTT* __restrict__ C,
                                               long za, long zb, long zc) {
  __shared__ u16 As[128 * 64];
  __shared__ u16 Bs[128 * 64];
  A += (long)blockIdx.z * za;
  Bw += (long)blockIdx.z * zb;
  C += (long)blockIdx.z * zc;
  const int tid = threadIdx.x;
  const int lane = tid & 63;
  const int l15 = lane & 15, lg = lane >> 4;
  const int wid = tid >> 6;
  const int wm = wid >> 1, wn = wid & 1;
  const long mbase = (long)blockIdx.y * 128;
  const long nbase = (long)blockIdx.x * 128;

  const u16* ap = A + (mbase + (tid >> 3)) * 1024 + (tid & 7) * 8;
  const u16* bp = Bw + (nbase + (tid >> 3)) * 1024 + (tid & 7) * 8;

  v4f acc[4][4] = {};

  for (int kt = 0; kt < 16; ++kt) {
    __syncthreads();
#pragma unroll
    for (int j = 0; j < 4; ++j) {
      gload_lds16(ap + kt * 64 + j * 32 * 1024, &As[(tid + 256 * j) * 8]);
      gload_lds16(bp + kt * 64 + j * 32 * 1024, &Bs[(tid + 256 * j) * 8]);
    }
    __syncthreads();
#pragma unroll
    for (int kk = 0; kk < 2; ++kk) {
      v8s a[4], b[4];
#pragma unroll
      for (int i = 0; i < 4; ++i)
        a[i] = *(const v8s*)&As[(wm * 64 + i * 16 + l15) * 64 + kk * 32 + lg * 8];
#pragma unroll
      for (int i = 0; i < 4; ++i)
        b[i] = *(const v8s*)&Bs[(wn * 64 + i * 16 + l15) * 64 + kk * 32 + lg * 8];
#pragma unroll
      for (int mi = 0; mi < 4; ++mi)
#pragma unroll
        for (int nj = 0; nj < 4; ++nj)
          acc[mi][nj] = __builtin_amdgcn_mfma_f32_16x16x32_bf16(a[mi], b[nj], acc[mi][nj], 0, 0, 0);
    }
  }
#pragma unroll
  for (int mi = 0; mi < 4; ++mi) {
#pragma unroll
    for (int r = 0; r < 4; ++r) {
      long row = mbase + wm * 64 + mi * 16 + lg * 4 + r;
#pragma unroll
      for (int nj = 0; nj < 4; ++nj) {
        long col = nbase + wn * 64 + nj * 16 + l15;
        if constexpr (__is_same(OUTT, float))
          C[row * 1024 + col] = acc[mi][nj][r];
        else
          C[row * 1024 + col] = f2b(acc[mi][nj][r]);
      }
    }
  }
}

// ---------------- fused masked attention, split-K x3 (chunk=6 tiles) ----------
// grid (48, 64): x -> (g = 15-(x/3), chunk c = x%3), heavy groups first.
// Chunk c covers tiles [c*6, min(ntiles, c*6+6)); inner loop identical to the
// round-10 best (67.7us). Unnormalized flash partials per slot; merge combines.
__global__ __launch_bounds__(256) void attn_kern(const u16* __restrict__ qb,
                                                 const u16* __restrict__ kb,
                                                 const u16* __restrict__ vb,
                                                 const int* __restrict__ valid,
                                                 const u16* __restrict__ perm,
                                                 u16* __restrict__ partO,
                                                 float* __restrict__ partM,
                                                 float* __restrict__ partL) {
  __shared__ u16 Ks[64 * 72];       // [key][hd], +8 pad -> no 16-way conflict
  __shared__ u16 Vt[64 * 72];       // [hd][key], transposed for PV B-operand
  __shared__ u16 Ps[4][16 * 72];    // per-wave P tile [q][key]

  const int tid = threadIdx.x;
  const int lane = tid & 63;
  const int wid = tid >> 6;
  const int l15 = lane & 15, lg = lane >> 4;
  const int bh = blockIdx.y;
  const int b = bh >> 4, h = bh & 15;
  const long headoff = ((long)b * LL) * DD + h * 64;
  const int xx = blockIdx.x;
  const int gq = 15 - (xx / 3);    // heaviest sorted group dispatched first
  const int ch = xx % 3;
  const u16* pblk = perm + bh * 1024 + gq * 64;

  const int lastv = valid[bh * LL + pblk[63]];
  const int ntiles = ((lastv == 0 ? LL : lastv) + 63) >> 6;
  const int kt0 = ch * 6;
  const int kt1 = min(ntiles, kt0 + 6);
  if (kt0 >= kt1) return;  // chunk absent for lighter groups
  const int slot = (bh * 16 + gq) * 3 + ch;

  const u16* pp = pblk + wid * 16;

  // Q A-fragments (rows via perm) live in registers for the whole kernel
  const int qrowA = pp[l15];
  v8s qf[2];
#pragma unroll
  for (int ks = 0; ks < 2; ++ks)
    qf[ks] = *(const v8s*)(qb + headoff + (long)qrowA * DD + ks * 32 + lg * 8);

  // per-lane C-frag rows (lg*4+r): raw valid for masking
  int vraw[4];
#pragma unroll
  for (int r = 0; r < 4; ++r) vraw[r] = valid[bh * LL + pp[lg * 4 + r]];

  float mrow[4], lrow[4];
  v4f oacc[4] = {};
#pragma unroll
  for (int r = 0; r < 4; ++r) { mrow[r] = -1e30f; lrow[r] = 0.0f; }

  const int kk = tid & 63;   // staging: key row
  const int qtr = tid >> 6;  // staging: 16-wide hd quarter
  const long stagebase = headoff + (long)kk * DD + qtr * 16;

  // prologue: issue first tile's K/V loads (reg staging, write-late)
  v8s rk0 = *(const v8s*)(kb + stagebase + (long)kt0 * 64 * DD);
  v8s rk1 = *(const v8s*)(kb + stagebase + (long)kt0 * 64 * DD + 8);
  v8s rv0 = *(const v8s*)(vb + stagebase + (long)kt0 * 64 * DD);
  v8s rv1 = *(const v8s*)(vb + stagebase + (long)kt0 * 64 * DD + 8);

  for (int kt = kt0; kt < kt1; ++kt) {
    // ---- barrier A (WAR guard): raw s_barrier, no vmcnt drain.
    __builtin_amdgcn_sched_barrier(0);
    __builtin_amdgcn_s_barrier();
    __builtin_amdgcn_sched_barrier(0);

    // commit staged regs -> LDS (compiler inserts COUNTED vmcnt for rk*/rv*)
    *(v8s*)&Ks[kk * 72 + qtr * 16] = rk0;
    *(v8s*)&Ks[kk * 72 + qtr * 16 + 8] = rk1;
    {
      v8u u0 = __builtin_bit_cast(v8u, rv0);
      v8u u1 = __builtin_bit_cast(v8u, rv1);
#pragma unroll
      for (int j = 0; j < 8; ++j) Vt[(qtr * 16 + j) * 72 + kk] = u0[j];
#pragma unroll
      for (int j = 0; j < 8; ++j) Vt[(qtr * 16 + 8 + j) * 72 + kk] = u1[j];
    }
    // prefetch next tile's K/V; stays in flight across barrier B + compute
    if (kt + 1 < kt1) {
      const long noff = stagebase + (long)(kt + 1) * 64 * DD;
      rk0 = *(const v8s*)(kb + noff);
      rk1 = *(const v8s*)(kb + noff + 8);
      rv0 = *(const v8s*)(vb + noff);
      rv1 = *(const v8s*)(vb + noff + 8);
    }
    // ---- barrier B: ds_writes visible; vmcnt NOT drained.
    asm volatile("s_waitcnt lgkmcnt(0)" ::: "memory");
    __builtin_amdgcn_sched_barrier(0);
    __builtin_amdgcn_s_barrier();
    __builtin_amdgcn_sched_barrier(0);

    // S = Q K^T for 16 q rows x 64 keys
    v4f s[4];
    __builtin_amdgcn_s_setprio(1);
#pragma unroll
    for (int t = 0; t < 4; ++t) {
      v4f z = {};
#pragma unroll
      for (int ks = 0; ks < 2; ++ks) {
        v8s kf = *(const v8s*)&Ks[(t * 16 + l15) * 72 + ks * 32 + lg * 8];
        z = __builtin_amdgcn_mfma_f32_16x16x32_bf16(qf[ks], kf, z, 0, 0, 0);
      }
      s[t] = z;
    }
    __builtin_amdgcn_s_setprio(0);

    // scale into log2 domain + mask (ref semantics: -1e6, col < valid_raw)
    const float SC = 0.18033688f;  // (1/8) * log2(e)
    const int colbase = kt * 64 + l15;
#pragma unroll
    for (int t = 0; t < 4; ++t)
#pragma unroll
      for (int r = 0; r < 4; ++r) {
        float val = s[t][r] * SC;
        s[t][r] = (colbase + t * 16 < vraw[r]) ? val : -1e6f;
      }

    // online softmax (log2 domain) with defer-max: rescale only if max grew >11
    float pm[4];
#pragma unroll
    for (int r = 0; r < 4; ++r)
      pm[r] = fmaxf(fmaxf(s[0][r], s[1][r]), fmaxf(s[2][r], s[3][r]));
#pragma unroll
    for (int d = 1; d < 16; d <<= 1)
#pragma unroll
      for (int r = 0; r < 4; ++r) pm[r] = fmaxf(pm[r], __shfl_xor(pm[r], d));

    bool sk = true;
#pragma unroll
    for (int r = 0; r < 4; ++r) sk = sk && (pm[r] <= mrow[r] + 11.0f);
    if (!__all(sk)) {
#pragma unroll
      for (int r = 0; r < 4; ++r) {
        float mn = fmaxf(mrow[r], pm[r]);
        float sc = __builtin_amdgcn_exp2f(mrow[r] - mn);
        mrow[r] = mn;
        lrow[r] *= sc;
#pragma unroll
        for (int t = 0; t < 4; ++t) oacc[t][r] *= sc;
      }
    }
    float rs[4] = {0.f, 0.f, 0.f, 0.f};
#pragma unroll
    for (int t = 0; t < 4; ++t)
#pragma unroll
      for (int r = 0; r < 4; ++r) {
        float p = __builtin_amdgcn_exp2f(s[t][r] - mrow[r]);
        s[t][r] = p;
        rs[r] += p;
      }
#pragma unroll
    for (int d = 1; d < 16; d <<= 1)
#pragma unroll
      for (int r = 0; r < 4; ++r) rs[r] += __shfl_xor(rs[r], d);
#pragma unroll
    for (int r = 0; r < 4; ++r) lrow[r] += rs[r];

    // P -> bf16 -> per-wave LDS, then consume as MFMA A-operand
#pragma unroll
    for (int t = 0; t < 4; ++t)
#pragma unroll
      for (int r = 0; r < 4; ++r)
        Ps[wid][(lg * 4 + r) * 72 + t * 16 + l15] = f2b(s[t][r]);

    asm volatile("s_waitcnt lgkmcnt(0)" ::: "memory");
    __builtin_amdgcn_sched_barrier(0);

    __builtin_amdgcn_s_setprio(1);
#pragma unroll
    for (int ks = 0; ks < 2; ++ks) {
      v8s pa = *(const v8s*)&Ps[wid][l15 * 72 + ks * 32 + lg * 8];
#pragma unroll
      for (int t = 0; t < 4; ++t) {
        v8s vf = *(const v8s*)&Vt[(t * 16 + l15) * 72 + ks * 32 + lg * 8];
        oacc[t] = __builtin_amdgcn_mfma_f32_16x16x32_bf16(pa, vf, oacc[t], 0, 0, 0);
      }
    }
    __builtin_amdgcn_s_setprio(0);
  }

  // epilogue: write UNNORMALIZED partials (sorted-row order); merge normalizes
  u16* po = partO + (long)slot * 4096;
  float* pmv = partM + slot * 64;
  float* plv = partL + slot * 64;
#pragma unroll
  for (int r = 0; r < 4; ++r) {
    int p = wid * 16 + lg * 4 + r;
    pmv[p] = mrow[r];
    plv[p] = lrow[r];
#pragma unroll
    for (int t = 0; t < 4; ++t)
      po[p * 64 + t * 16 + l15] = f2b(oacc[t][r]);
  }
}

// ---------------- merge the (up to 3) chunk partials per (bh, group) ----------
__global__ __launch_bounds__(256) void merge_kern(const int* __restrict__ valid,
                                                  const u16* __restrict__ perm,
                                                  const u16* __restrict__ partO,
                                                  const float* __restrict__ partM,
                                                  const float* __restrict__ partL,
                                                  u16* __restrict__ ob) {
  const int g = blockIdx.x, bh = blockIdx.y;
  const int b = bh >> 4, h = bh & 15;
  const u16* pblk = perm + bh * 1024 + g * 64;
  const int lastv = valid[bh * LL + pblk[63]];
  const int ntiles = ((lastv == 0 ? LL : lastv) + 63) >> 6;
  const int nch = min(3, (ntiles + 5) / 6);  // chunks present (chunk = 6 tiles)
  const int p = threadIdx.x >> 2;          // sorted row 0..63
  const int q4 = (threadIdx.x & 3) * 16;   // col base
  const int s0 = (bh * 16 + g) * 3;

  float m[3], l[3];
  float M = -1e30f;
  for (int c = 0; c < nch; ++c) {
    m[c] = partM[(s0 + c) * 64 + p];
    l[c] = partL[(s0 + c) * 64 + p];
    M = fmaxf(M, m[c]);
  }
  float w[3], L = 0.0f;
  for (int c = 0; c < nch; ++c) {
    w[c] = __builtin_amdgcn_exp2f(m[c] - M);
    L += l[c] * w[c];
  }
  const float inv = 1.0f / L;

  float acc[16];
#pragma unroll
  for (int j = 0; j < 16; ++j) acc[j] = 0.0f;
  for (int c = 0; c < nch; ++c) {
    const u16* po = partO + (long)(s0 + c) * 4096 + p * 64 + q4;
    v8u x0 = *(const v8u*)po;
    v8u x1 = *(const v8u*)(po + 8);
#pragma unroll
    for (int j = 0; j < 8; ++j) acc[j] += b2f(x0[j]) * w[c];
#pragma unroll
    for (int j = 0; j < 8; ++j) acc[8 + j] += b2f(x1[j]) * w[c];
  }
  const int orow = pblk[p];
  u16* dst = ob + ((long)b * LL + orow) * DD + h * 64 + q4;
#pragma unroll
  for (int j = 0; j < 16; ++j) dst[j] = f2b(acc[j] * inv);
}

// ---------------- launch ------------------------------------------------------
extern "C" void kernel_launch(void* const* d_in, const int* in_sizes, int n_in,
                              void* d_out, int out_size, void* d_ws, size_t ws_size,
                              hipStream_t stream) {
  const float* Q = (const float*)d_in[0];
  const float* K = (const float*)d_in[1];
  const float* V = (const float*)d_in[2];
  const int* valid = (const int*)d_in[3];
  const float* Wq = (const float*)d_in[4];
  const float* Wk = (const float*)d_in[5];
  const float* Wv = (const float*)d_in[6];
  const float* Wo = (const float*)d_in[7];
  float* out = (float*)d_out;

  u16* ws = (u16*)d_ws;
  const long MK = 4096L * 1024;
  const long NK = 1024L * 1024;
  u16* qkvb = ws;              // bf16 Q,K,V  3*MK (dead after proj GEMM)
  u16* wqkv = qkvb + 3 * MK;   // bf16 Wq,Wk,Wv 3*NK (dead after proj GEMM)
  u16* wo = wqkv + 3 * NK;     // bf16 Wo NK
  u16* proj = wo + NK;         // q,k,v projections 3*MK
  u16* ob = proj + 3 * MK;     // attention output MK
  // dead-region reuse after proj GEMM:
  u16* perm = wqkv;                                  // 64*1024 u16 = 128 KB
  u16* partO = qkvb;                                 // 3072 slots*4096 u16 = 25.2 MB (exact fit)
  float* partM = (float*)(wqkv + 64 * 1024);         // 3072*64 f32 = 786 KB
  float* partL = partM + 3072L * 64;                 // 786 KB

  cvt7<<<dim3(2048, 7), 256, 0, stream>>>(Q, K, V, Wq, Wk, Wv, Wo, ws);

  gemm_bt<u16><<<dim3(8, 32, 3), 256, 0, stream>>>(qkvb, wqkv, proj, MK, NK, MK);
  sortperm<<<64, 256, 0, stream>>>(valid, perm);
  attn_kern<<<dim3(48, 64), 256, 0, stream>>>(proj, proj + MK, proj + 2 * MK, valid,
                                              perm, partO, partM, partL);
  merge_kern<<<dim3(16, 64), 256, 0, stream>>>(valid, perm, partO, partM, partL, ob);
  gemm_bt<float><<<dim3(8, 32, 1), 256, 0, stream>>>(ob, wo, out, 0, 0, 0);
}

// Round 17
// 137.371 us; speedup vs baseline: 7.9421x; 1.0279x over previous
//
#include <hip/hip_runtime.h>
#include <hip/hip_bf16.h>

typedef short v8s __attribute__((ext_vector_type(8)));
typedef unsigned short v8u __attribute__((ext_vector_type(8)));
typedef float v4f __attribute__((ext_vector_type(4)));
typedef unsigned short u16;

#define LL 1024
#define DD 1024

static __device__ __forceinline__ u16 f2b(float x) {
  __hip_bfloat16 h = __float2bfloat16(x);
  return __builtin_bit_cast(u16, h);
}
static __device__ __forceinline__ float b2f(u16 u) {
  unsigned int x = ((unsigned int)u) << 16;
  return __builtin_bit_cast(float, x);
}

static __device__ __forceinline__ void gload_lds16(const u16* g, u16* l) {
  __builtin_amdgcn_global_load_lds((const __attribute__((address_space(1))) void*)g,
                                   (__attribute__((address_space(3))) void*)l, 16, 0, 0);
}

// ---------------- f32 -> bf16 conversion, ALL 7 tensors in one launch --------
__global__ __launch_bounds__(256) void cvt7(const float* __restrict__ p0,
                                            const float* __restrict__ p1,
                                            const float* __restrict__ p2,
                                            const float* __restrict__ p3,
                                            const float* __restrict__ p4,
                                            const float* __restrict__ p5,
                                            const float* __restrict__ p6,
                                            u16* __restrict__ ws) {
  const long MK = 4096L * 1024, NK = 1024L * 1024;
  const int y = blockIdx.y;
  const float* srcs[7] = {p0, p1, p2, p3, p4, p5, p6};
  const float* src = srcs[y];
  u16* dst = (y < 3) ? ws + (long)y * MK : ws + 3 * MK + (long)(y - 3) * NK;
  const int n8 = (y < 3) ? (int)(MK / 8) : (int)(NK / 8);
  int i = blockIdx.x * 256 + threadIdx.x;
  if (i >= n8) return;
  const float4* p = (const float4*)src + (long)i * 2;
  float4 a = p[0], b = p[1];
  v8u r;
  r[0] = f2b(a.x); r[1] = f2b(a.y); r[2] = f2b(a.z); r[3] = f2b(a.w);
  r[4] = f2b(b.x); r[5] = f2b(b.y); r[6] = f2b(b.z); r[7] = f2b(b.w);
  *((v8u*)dst + i) = r;
}

// ---------------- per-head counting sort of q-rows by effective valid len ----
__global__ __launch_bounds__(256) void sortperm(const int* __restrict__ valid,
                                                u16* __restrict__ perm) {
  __shared__ int hist[1024];
  __shared__ int wsum[4];
  const int bh = blockIdx.x;
  const int tid = threadIdx.x;
  const int* v = valid + bh * 1024;
  for (int i = tid; i < 1024; i += 256) hist[i] = 0;
  __syncthreads();
  for (int i = tid; i < 1024; i += 256) {
    int k = v[i];
    k = (k == 0) ? 1023 : (k - 1);  // bin = eff-1
    atomicAdd(&hist[k], 1);
  }
  __syncthreads();
  const int base = tid * 4;
  int h0 = hist[base], h1 = hist[base + 1], h2 = hist[base + 2], h3 = hist[base + 3];
  int local = h0 + h1 + h2 + h3;
  const int lane = tid & 63, w = tid >> 6;
  int scan = local;
#pragma unroll
  for (int d = 1; d < 64; d <<= 1) {
    int t = __shfl_up(scan, d);
    if (lane >= d) scan += t;
  }
  if (lane == 63) wsum[w] = scan;
  __syncthreads();
  int woff = 0;
  for (int i = 0; i < w; ++i) woff += wsum[i];
  int excl = woff + scan - local;
  hist[base] = excl;
  hist[base + 1] = excl + h0;
  hist[base + 2] = excl + h0 + h1;
  hist[base + 3] = excl + h0 + h1 + h2;
  __syncthreads();
  for (int i = tid; i < 1024; i += 256) {
    int k = v[i];
    k = (k == 0) ? 1023 : (k - 1);
    int pos = atomicAdd(&hist[k], 1);
    perm[bh * 1024 + pos] = (u16)i;
  }
}

// ---------------- C[M,N] = A[M,K] * B[N,K]^T, 128x128 tile (proj GEMM) --------
template <typename OUTT>
__global__ __launch_bounds__(256) void gemm_bt(const u16* __restrict__ A,
                                               const u16* __restrict__ Bw,
                                               OUTT* __restrict__ C,
                                               long za, long zb, long zc) {
  __shared__ u16 As[128 * 64];
  __shared__ u16 Bs[128 * 64];
  A += (long)blockIdx.z * za;
  Bw += (long)blockIdx.z * zb;
  C += (long)blockIdx.z * zc;
  const int tid = threadIdx.x;
  const int lane = tid & 63;
  const int l15 = lane & 15, lg = lane >> 4;
  const int wid = tid >> 6;
  const int wm = wid >> 1, wn = wid & 1;
  const long mbase = (long)blockIdx.y * 128;
  const long nbase = (long)blockIdx.x * 128;

  const u16* ap = A + (mbase + (tid >> 3)) * 1024 + (tid & 7) * 8;
  const u16* bp = Bw + (nbase + (tid >> 3)) * 1024 + (tid & 7) * 8;

  v4f acc[4][4] = {};

  for (int kt = 0; kt < 16; ++kt) {
    __syncthreads();
#pragma unroll
    for (int j = 0; j < 4; ++j) {
      gload_lds16(ap + kt * 64 + j * 32 * 1024, &As[(tid + 256 * j) * 8]);
      gload_lds16(bp + kt * 64 + j * 32 * 1024, &Bs[(tid + 256 * j) * 8]);
    }
    __syncthreads();
#pragma unroll
    for (int kk = 0; kk < 2; ++kk) {
      v8s a[4], b[4];
#pragma unroll
      for (int i = 0; i < 4; ++i)
        a[i] = *(const v8s*)&As[(wm * 64 + i * 16 + l15) * 64 + kk * 32 + lg * 8];
#pragma unroll
      for (int i = 0; i < 4; ++i)
        b[i] = *(const v8s*)&Bs[(wn * 64 + i * 16 + l15) * 64 + kk * 32 + lg * 8];
#pragma unroll
      for (int mi = 0; mi < 4; ++mi)
#pragma unroll
        for (int nj = 0; nj < 4; ++nj)
          acc[mi][nj] = __builtin_amdgcn_mfma_f32_16x16x32_bf16(a[mi], b[nj], acc[mi][nj], 0, 0, 0);
    }
  }
#pragma unroll
  for (int mi = 0; mi < 4; ++mi) {
#pragma unroll
    for (int r = 0; r < 4; ++r) {
      long row = mbase + wm * 64 + mi * 16 + lg * 4 + r;
#pragma unroll
      for (int nj = 0; nj < 4; ++nj) {
        long col = nbase + wn * 64 + nj * 16 + l15;
        if constexpr (__is_same(OUTT, float))
          C[row * 1024 + col] = acc[mi][nj][r];
        else
          C[row * 1024 + col] = f2b(acc[mi][nj][r]);
      }
    }
  }
}

// ---------------- C[M,N] = A[M,K] * B[N,K]^T, 64x128 tile (out GEMM) ----------
// grid (8, 64): 512 blocks = 2/CU (vs 1/CU at 128x128) -> inter-block overlap
// hides the barrier-drain stalls (attn round-16 lesson: latency regime favors
// resident-block count over per-block efficiency). f32 output to d_out.
__global__ __launch_bounds__(256) void gemm_bt64(const u16* __restrict__ A,
                                                 const u16* __restrict__ Bw,
                                                 float* __restrict__ C) {
  __shared__ u16 As[64 * 64];
  __shared__ u16 Bs[128 * 64];
  const int tid = threadIdx.x;
  const int lane = tid & 63;
  const int l15 = lane & 15, lg = lane >> 4;
  const int wid = tid >> 6;
  const int wm = wid >> 1, wn = wid & 1;  // wave = 32 rows x 64 cols
  const long mbase = (long)blockIdx.y * 64;
  const long nbase = (long)blockIdx.x * 128;

  const u16* ap = A + (mbase + (tid >> 3)) * 1024 + (tid & 7) * 8;
  const u16* bp = Bw + (nbase + (tid >> 3)) * 1024 + (tid & 7) * 8;

  v4f acc[2][4] = {};

  for (int kt = 0; kt < 16; ++kt) {
    __syncthreads();
#pragma unroll
    for (int j = 0; j < 2; ++j)
      gload_lds16(ap + kt * 64 + j * 32 * 1024, &As[(tid + 256 * j) * 8]);
#pragma unroll
    for (int j = 0; j < 4; ++j)
      gload_lds16(bp + kt * 64 + j * 32 * 1024, &Bs[(tid + 256 * j) * 8]);
    __syncthreads();
#pragma unroll
    for (int kk = 0; kk < 2; ++kk) {
      v8s a[2], b[4];
#pragma unroll
      for (int i = 0; i < 2; ++i)
        a[i] = *(const v8s*)&As[(wm * 32 + i * 16 + l15) * 64 + kk * 32 + lg * 8];
#pragma unroll
      for (int i = 0; i < 4; ++i)
        b[i] = *(const v8s*)&Bs[(wn * 64 + i * 16 + l15) * 64 + kk * 32 + lg * 8];
#pragma unroll
      for (int mi = 0; mi < 2; ++mi)
#pragma unroll
        for (int nj = 0; nj < 4; ++nj)
          acc[mi][nj] = __builtin_amdgcn_mfma_f32_16x16x32_bf16(a[mi], b[nj], acc[mi][nj], 0, 0, 0);
    }
  }
#pragma unroll
  for (int mi = 0; mi < 2; ++mi) {
#pragma unroll
    for (int r = 0; r < 4; ++r) {
      long row = mbase + wm * 32 + mi * 16 + lg * 4 + r;
#pragma unroll
      for (int nj = 0; nj < 4; ++nj) {
        long col = nbase + wn * 64 + nj * 16 + l15;
        C[row * 1024 + col] = acc[mi][nj][r];
      }
    }
  }
}

// ---------------- fused masked attention, split-K x3 (chunk=6 tiles) ----------
__global__ __launch_bounds__(256) void attn_kern(const u16* __restrict__ qb,
                                                 const u16* __restrict__ kb,
                                                 const u16* __restrict__ vb,
                                                 const int* __restrict__ valid,
                                                 const u16* __restrict__ perm,
                                                 u16* __restrict__ partO,
                                                 float* __restrict__ partM,
                                                 float* __restrict__ partL) {
  __shared__ u16 Ks[64 * 72];       // [key][hd], +8 pad -> no 16-way conflict
  __shared__ u16 Vt[64 * 72];       // [hd][key], transposed for PV B-operand
  __shared__ u16 Ps[4][16 * 72];    // per-wave P tile [q][key]

  const int tid = threadIdx.x;
  const int lane = tid & 63;
  const int wid = tid >> 6;
  const int l15 = lane & 15, lg = lane >> 4;
  const int bh = blockIdx.y;
  const int b = bh >> 4, h = bh & 15;
  const long headoff = ((long)b * LL) * DD + h * 64;
  const int xx = blockIdx.x;
  const int gq = 15 - (xx / 3);    // heaviest sorted group dispatched first
  const int ch = xx % 3;
  const u16* pblk = perm + bh * 1024 + gq * 64;

  const int lastv = valid[bh * LL + pblk[63]];
  const int ntiles = ((lastv == 0 ? LL : lastv) + 63) >> 6;
  const int kt0 = ch * 6;
  const int kt1 = min(ntiles, kt0 + 6);
  if (kt0 >= kt1) return;  // chunk absent for lighter groups
  const int slot = (bh * 16 + gq) * 3 + ch;

  const u16* pp = pblk + wid * 16;

  // Q A-fragments (rows via perm) live in registers for the whole kernel
  const int qrowA = pp[l15];
  v8s qf[2];
#pragma unroll
  for (int ks = 0; ks < 2; ++ks)
    qf[ks] = *(const v8s*)(qb + headoff + (long)qrowA * DD + ks * 32 + lg * 8);

  // per-lane C-frag rows (lg*4+r): raw valid for masking
  int vraw[4];
#pragma unroll
  for (int r = 0; r < 4; ++r) vraw[r] = valid[bh * LL + pp[lg * 4 + r]];

  float mrow[4], lrow[4];
  v4f oacc[4] = {};
#pragma unroll
  for (int r = 0; r < 4; ++r) { mrow[r] = -1e30f; lrow[r] = 0.0f; }

  const int kk = tid & 63;   // staging: key row
  const int qtr = tid >> 6;  // staging: 16-wide hd quarter
  const long stagebase = headoff + (long)kk * DD + qtr * 16;

  // prologue: issue first tile's K/V loads (reg staging, write-late)
  v8s rk0 = *(const v8s*)(kb + stagebase + (long)kt0 * 64 * DD);
  v8s rk1 = *(const v8s*)(kb + stagebase + (long)kt0 * 64 * DD + 8);
  v8s rv0 = *(const v8s*)(vb + stagebase + (long)kt0 * 64 * DD);
  v8s rv1 = *(const v8s*)(vb + stagebase + (long)kt0 * 64 * DD + 8);

  for (int kt = kt0; kt < kt1; ++kt) {
    // ---- barrier A (WAR guard): raw s_barrier, no vmcnt drain.
    __builtin_amdgcn_sched_barrier(0);
    __builtin_amdgcn_s_barrier();
    __builtin_amdgcn_sched_barrier(0);

    // commit staged regs -> LDS (compiler inserts COUNTED vmcnt for rk*/rv*)
    *(v8s*)&Ks[kk * 72 + qtr * 16] = rk0;
    *(v8s*)&Ks[kk * 72 + qtr * 16 + 8] = rk1;
    {
      v8u u0 = __builtin_bit_cast(v8u, rv0);
      v8u u1 = __builtin_bit_cast(v8u, rv1);
#pragma unroll
      for (int j = 0; j < 8; ++j) Vt[(qtr * 16 + j) * 72 + kk] = u0[j];
#pragma unroll
      for (int j = 0; j < 8; ++j) Vt[(qtr * 16 + 8 + j) * 72 + kk] = u1[j];
    }
    // prefetch next tile's K/V; stays in flight across barrier B + compute
    if (kt + 1 < kt1) {
      const long noff = stagebase + (long)(kt + 1) * 64 * DD;
      rk0 = *(const v8s*)(kb + noff);
      rk1 = *(const v8s*)(kb + noff + 8);
      rv0 = *(const v8s*)(vb + noff);
      rv1 = *(const v8s*)(vb + noff + 8);
    }
    // ---- barrier B: ds_writes visible; vmcnt NOT drained.
    asm volatile("s_waitcnt lgkmcnt(0)" ::: "memory");
    __builtin_amdgcn_sched_barrier(0);
    __builtin_amdgcn_s_barrier();
    __builtin_amdgcn_sched_barrier(0);

    // S = Q K^T for 16 q rows x 64 keys
    v4f s[4];
    __builtin_amdgcn_s_setprio(1);
#pragma unroll
    for (int t = 0; t < 4; ++t) {
      v4f z = {};
#pragma unroll
      for (int ks = 0; ks < 2; ++ks) {
        v8s kf = *(const v8s*)&Ks[(t * 16 + l15) * 72 + ks * 32 + lg * 8];
        z = __builtin_amdgcn_mfma_f32_16x16x32_bf16(qf[ks], kf, z, 0, 0, 0);
      }
      s[t] = z;
    }
    __builtin_amdgcn_s_setprio(0);

    // scale into log2 domain + mask (ref semantics: -1e6, col < valid_raw)
    const float SC = 0.18033688f;  // (1/8) * log2(e)
    const int colbase = kt * 64 + l15;
#pragma unroll
    for (int t = 0; t < 4; ++t)
#pragma unroll
      for (int r = 0; r < 4; ++r) {
        float val = s[t][r] * SC;
        s[t][r] = (colbase + t * 16 < vraw[r]) ? val : -1e6f;
      }

    // online softmax (log2 domain) with defer-max: rescale only if max grew >11
    float pm[4];
#pragma unroll
    for (int r = 0; r < 4; ++r)
      pm[r] = fmaxf(fmaxf(s[0][r], s[1][r]), fmaxf(s[2][r], s[3][r]));
#pragma unroll
    for (int d = 1; d < 16; d <<= 1)
#pragma unroll
      for (int r = 0; r < 4; ++r) pm[r] = fmaxf(pm[r], __shfl_xor(pm[r], d));

    bool sk = true;
#pragma unroll
    for (int r = 0; r < 4; ++r) sk = sk && (pm[r] <= mrow[r] + 11.0f);
    if (!__all(sk)) {
#pragma unroll
      for (int r = 0; r < 4; ++r) {
        float mn = fmaxf(mrow[r], pm[r]);
        float sc = __builtin_amdgcn_exp2f(mrow[r] - mn);
        mrow[r] = mn;
        lrow[r] *= sc;
#pragma unroll
        for (int t = 0; t < 4; ++t) oacc[t][r] *= sc;
      }
    }
    float rs[4] = {0.f, 0.f, 0.f, 0.f};
#pragma unroll
    for (int t = 0; t < 4; ++t)
#pragma unroll
      for (int r = 0; r < 4; ++r) {
        float p = __builtin_amdgcn_exp2f(s[t][r] - mrow[r]);
        s[t][r] = p;
        rs[r] += p;
      }
#pragma unroll
    for (int d = 1; d < 16; d <<= 1)
#pragma unroll
      for (int r = 0; r < 4; ++r) rs[r] += __shfl_xor(rs[r], d);
#pragma unroll
    for (int r = 0; r < 4; ++r) lrow[r] += rs[r];

    // P -> bf16 -> per-wave LDS, then consume as MFMA A-operand
#pragma unroll
    for (int t = 0; t < 4; ++t)
#pragma unroll
      for (int r = 0; r < 4; ++r)
        Ps[wid][(lg * 4 + r) * 72 + t * 16 + l15] = f2b(s[t][r]);

    asm volatile("s_waitcnt lgkmcnt(0)" ::: "memory");
    __builtin_amdgcn_sched_barrier(0);

    __builtin_amdgcn_s_setprio(1);
#pragma unroll
    for (int ks = 0; ks < 2; ++ks) {
      v8s pa = *(const v8s*)&Ps[wid][l15 * 72 + ks * 32 + lg * 8];
#pragma unroll
      for (int t = 0; t < 4; ++t) {
        v8s vf = *(const v8s*)&Vt[(t * 16 + l15) * 72 + ks * 32 + lg * 8];
        oacc[t] = __builtin_amdgcn_mfma_f32_16x16x32_bf16(pa, vf, oacc[t], 0, 0, 0);
      }
    }
    __builtin_amdgcn_s_setprio(0);
  }

  // epilogue: write UNNORMALIZED partials (sorted-row order); merge normalizes
  u16* po = partO + (long)slot * 4096;
  float* pmv = partM + slot * 64;
  float* plv = partL + slot * 64;
#pragma unroll
  for (int r = 0; r < 4; ++r) {
    int p = wid * 16 + lg * 4 + r;
    pmv[p] = mrow[r];
    plv[p] = lrow[r];
#pragma unroll
    for (int t = 0; t < 4; ++t)
      po[p * 64 + t * 16 + l15] = f2b(oacc[t][r]);
  }
}

// ---------------- merge the (up to 3) chunk partials per (bh, group) ----------
__global__ __launch_bounds__(256) void merge_kern(const int* __restrict__ valid,
                                                  const u16* __restrict__ perm,
                                                  const u16* __restrict__ partO,
                                                  const float* __restrict__ partM,
                                                  const float* __restrict__ partL,
                                                  u16* __restrict__ ob) {
  const int g = blockIdx.x, bh = blockIdx.y;
  const int b = bh >> 4, h = bh & 15;
  const u16* pblk = perm + bh * 1024 + g * 64;
  const int lastv = valid[bh * LL + pblk[63]];
  const int ntiles = ((lastv == 0 ? LL : lastv) + 63) >> 6;
  const int nch = min(3, (ntiles + 5) / 6);  // chunks present (chunk = 6 tiles)
  const int p = threadIdx.x >> 2;          // sorted row 0..63
  const int q4 = (threadIdx.x & 3) * 16;   // col base
  const int s0 = (bh * 16 + g) * 3;

  float m[3], l[3];
  float M = -1e30f;
  for (int c = 0; c < nch; ++c) {
    m[c] = partM[(s0 + c) * 64 + p];
    l[c] = partL[(s0 + c) * 64 + p];
    M = fmaxf(M, m[c]);
  }
  float w[3], L = 0.0f;
  for (int c = 0; c < nch; ++c) {
    w[c] = __builtin_amdgcn_exp2f(m[c] - M);
    L += l[c] * w[c];
  }
  const float inv = 1.0f / L;

  float acc[16];
#pragma unroll
  for (int j = 0; j < 16; ++j) acc[j] = 0.0f;
  for (int c = 0; c < nch; ++c) {
    const u16* po = partO + (long)(s0 + c) * 4096 + p * 64 + q4;
    v8u x0 = *(const v8u*)po;
    v8u x1 = *(const v8u*)(po + 8);
#pragma unroll
    for (int j = 0; j < 8; ++j) acc[j] += b2f(x0[j]) * w[c];
#pragma unroll
    for (int j = 0; j < 8; ++j) acc[8 + j] += b2f(x1[j]) * w[c];
  }
  const int orow = pblk[p];
  u16* dst = ob + ((long)b * LL + orow) * DD + h * 64 + q4;
#pragma unroll
  for (int j = 0; j < 16; ++j) dst[j] = f2b(acc[j] * inv);
}

// ---------------- launch ------------------------------------------------------
extern "C" void kernel_launch(void* const* d_in, const int* in_sizes, int n_in,
                              void* d_out, int out_size, void* d_ws, size_t ws_size,
                              hipStream_t stream) {
  const float* Q = (const float*)d_in[0];
  const float* K = (const float*)d_in[1];
  const float* V = (const float*)d_in[2];
  const int* valid = (const int*)d_in[3];
  const float* Wq = (const float*)d_in[4];
  const float* Wk = (const float*)d_in[5];
  const float* Wv = (const float*)d_in[6];
  const float* Wo = (const float*)d_in[7];
  float* out = (float*)d_out;

  u16* ws = (u16*)d_ws;
  const long MK = 4096L * 1024;
  const long NK = 1024L * 1024;
  u16* qkvb = ws;              // bf16 Q,K,V  3*MK (dead after proj GEMM)
  u16* wqkv = qkvb + 3 * MK;   // bf16 Wq,Wk,Wv 3*NK (dead after proj GEMM)
  u16* wo = wqkv + 3 * NK;     // bf16 Wo NK
  u16* proj = wo + NK;         // q,k,v projections 3*MK
  u16* ob = proj + 3 * MK;     // attention output MK
  // dead-region reuse after proj GEMM:
  u16* perm = wqkv;                                  // 64*1024 u16 = 128 KB
  u16* partO = qkvb;                                 // 3072 slots*4096 u16 = 25.2 MB (exact fit)
  float* partM = (float*)(wqkv + 64 * 1024);         // 3072*64 f32 = 786 KB
  float* partL = partM + 3072L * 64;                 // 786 KB

  cvt7<<<dim3(2048, 7), 256, 0, stream>>>(Q, K, V, Wq, Wk, Wv, Wo, ws);

  gemm_bt<u16><<<dim3(8, 32, 3), 256, 0, stream>>>(qkvb, wqkv, proj, MK, NK, MK);
  sortperm<<<64, 256, 0, stream>>>(valid, perm);
  attn_kern<<<dim3(48, 64), 256, 0, stream>>>(proj, proj + MK, proj + 2 * MK, valid,
                                              perm, partO, partM, partL);
  merge_kern<<<dim3(16, 64), 256, 0, stream>>>(valid, perm, partO, partM, partL, ob);
  gemm_bt64<<<dim3(8, 64), 256, 0, stream>>>(ob, wo, out);
}